// Round 11
// baseline (2247.256 us; speedup 1.0000x reference)
//
#include <hip/hip_runtime.h>
#include <hip/hip_bf16.h>
#include <cstdint>
#include <cstddef>

// Problem constants
#define Bq 16
#define Sq 512
#define Dq 1024
#define Hq 16
#define Lq 4
#define FFq 4096
#define Mq (Bq * Sq)  // 8192

typedef unsigned short ushort_t;
typedef __attribute__((ext_vector_type(8))) short short8;
typedef __attribute__((ext_vector_type(8))) unsigned short ushortx8;
typedef __attribute__((ext_vector_type(4))) unsigned short ushortx4;
typedef __attribute__((ext_vector_type(4))) float floatx4;
typedef __attribute__((ext_vector_type(16))) float floatx16;

__device__ __forceinline__ float bf2f(ushort_t u) {
  union { unsigned int i; float f; } x;
  x.i = ((unsigned int)u) << 16;
  return x.f;
}
__device__ __forceinline__ ushort_t f2bf(float f) {
  unsigned int u = __float_as_uint(f);
  u += 0x7fffu + ((u >> 16) & 1u);
  return (ushort_t)(u >> 16);
}

// async global->LDS, 16B per lane; LDS dest is wave-uniform base + lane*16
#define GLL16(gp, lp) __builtin_amdgcn_global_load_lds( \
    (__attribute__((address_space(1))) void*)(gp),      \
    (__attribute__((address_space(3))) void*)(lp), 16, 0, 0)

// ---------------------------------------------------------------------------
// dtype probe: pe[1] (= cos(0) = 1.0) and ln1_g[0] (= 1.0).
// ---------------------------------------------------------------------------
__global__ void probe_kernel(const ushort_t* __restrict__ pe,
                             const ushort_t* __restrict__ g1,
                             int* __restrict__ flags)
{
  if (threadIdx.x == 0 && blockIdx.x == 0) {
    flags[0] = (pe[1] == (ushort_t)0x3F80u) ? 1 : 0;
    flags[1] = (g1[0] == (ushort_t)0x3F80u) ? 1 : 0;
  }
}

// fused small-tensor canonicalize: 10 segments in one dispatch
struct CvtArgs {
  const void* src[10];
  ushort_t*   dst[10];
  int         n[10];
  int         fi[10];
  int         cum[11];
};
__global__ __launch_bounds__(256) void convert_all_kernel(
    CvtArgs a, const int* __restrict__ flags)
{
  const int bidx = blockIdx.x;
  int s = 0;
  while (s < 9 && bidx >= a.cum[s + 1]) ++s;
  const int i = (bidx - a.cum[s]) * 256 + threadIdx.x;
  if (i >= a.n[s]) return;
  if (flags[a.fi[s]]) a.dst[s][i] = ((const ushort_t*)a.src[s])[i];
  else                a.dst[s][i] = f2bf(((const float*)a.src[s])[i]);
}

// ---------------------------------------------------------------------------
// 128x128 / 32x32x16-MFMA GEMM, split-K capable, GRANULE-MAJOR LDS.
// r10 post-mortem: the row-major [128][32] tile made each 32-row operand
// read touch 32B-used/64B-skipped per row -> 16 bank rounds instead of 8
// (SQ_LDS_BANK_CONFLICT saturated at 2^23). Fix: store 16B granules
// granule-major: slot = g*128 + row. Each ds_read_b128 then covers two
// CONTIGUOUS 512B runs (lanes 0-31 -> granule 2sl, lanes 32-63 -> 2sl+1)
// = perfect 8 rounds, zero conflicts, no swizzle. Staging stays legal:
// wave writes 64 contiguous slots; the per-lane GLOBAL source address
// carries the permutation (rule 21: permuted-source + linear-dest +
// matching read). k placement identical to the r9/r10-verified mapping.
// Model: time ~ staged_bytes/(resident_blocks x 4 waves x ~1.3 B/cyc);
// split-K keeps grid >= 1024 so 4-5 blocks/CU are resident.
// C/D layout (m74/m101): col=lane&31, row=(reg&3)+8*(reg>>2)+4*(lane>>5).
// ---------------------------------------------------------------------------
__global__ __launch_bounds__(256, 5) void gemm128_kernel(
    const ushort_t* __restrict__ A0, const ushort_t* __restrict__ BT0,
    const ushort_t* __restrict__ bias0, ushort_t* __restrict__ C0, int koff0,
    const ushort_t* __restrict__ A1, const ushort_t* __restrict__ BT1,
    const ushort_t* __restrict__ bias1, ushort_t* __restrict__ C1, int koff1,
    int N, int Kst, int Klen, int relu)
{
  __shared__ __align__(16) ushort_t As[2][128 * 32];  // 8 KB per buf
  __shared__ __align__(16) ushort_t Bs[2][128 * 32];  // 8 KB per buf

  const ushort_t* A    = blockIdx.z ? A1 : A0;
  const ushort_t* BT   = blockIdx.z ? BT1 : BT0;
  const ushort_t* bias = blockIdx.z ? bias1 : bias0;
  ushort_t*       C    = blockIdx.z ? C1 : C0;
  const int       koff = blockIdx.z ? koff1 : koff0;

  const int t = threadIdx.x;
  const int l = t & 63;
  const int wid = t >> 6;
  const int l31 = l & 31;
  const int wr = wid >> 1;   // wave M-half
  const int wc = wid & 1;    // wave N-half

  // ---- T1 XCD slab swizzle (bijective; gy = 64, multiple of 8) ----
  int bx = blockIdx.x, by = blockIdx.y;
  {
    const int gx = gridDim.x, gy = gridDim.y;
    if ((gy & 7) == 0) {
      const int orig = by * gx + bx;
      const int xcd = orig & 7;
      const int local = orig >> 3;
      const int rows = gy >> 3;
      by = xcd * rows + local % rows;
      bx = local / rows;
    }
  }
  const long m0 = (long)by * 128;
  const long n0 = (long)bx * 128;
  const int nk = Klen >> 5;

  // staging (granule-major): call c, wave w, lane ln covers LDS slot
  // s = c*256 + w*64 + ln  ->  granule g = c*2 + (w>>1), row = (w&1)*64+ln.
  // Source: A[(m0+row)*Kst + koff + kt*32 + g*8]; call c adds +16 elems.
  const int srow = (wid & 1) * 64 + l;
  const int gb8  = (wid >> 1) * 8;
  const ushort_t* sA = A + (m0 + srow) * (long)Kst + koff + gb8;
  const ushort_t* sB = BT + (n0 + srow) * (long)Kst + koff + gb8;
  const int lws = wid * 512;   // wave-uniform LDS elem base per call

#define STG(buf_, kt_) do {                                            \
    const long ko_ = (long)(kt_) << 5;                                 \
    GLL16(sA + ko_,      &As[(buf_)][lws]);                            \
    GLL16(sA + ko_ + 16, &As[(buf_)][2048 + lws]);                     \
    GLL16(sB + ko_,      &Bs[(buf_)][lws]);                            \
    GLL16(sB + ko_ + 16, &Bs[(buf_)][2048 + lws]);                     \
  } while (0)

  floatx16 acc[2][2];
#pragma unroll
  for (int i = 0; i < 2; ++i)
#pragma unroll
    for (int j = 0; j < 2; ++j)
#pragma unroll
      for (int r = 0; r < 16; ++r) acc[i][j][r] = 0.0f;

  // frag reads: elem = (g*128 + row)*8, g = sl*2 + (l>>5),
  // row = w*64 + fr*32 + l31  ->  co_sl + row*8 (+fr*256)
  const int co0 = ((0 * 2 + (l >> 5)) * 128) * 8;   // k-slice 0
  const int co1 = ((2 + (l >> 5)) * 128) * 8;       // k-slice 1
  const int arow = (wr * 64 + l31) * 8;             // + fr*256
  const int brow = (wc * 64 + l31) * 8;             // + fc*256

  STG(0, 0);
  __syncthreads();

  for (int kt = 0; kt < nk; ++kt) {
    const int buf = kt & 1;
    if (kt + 1 < nk) STG(buf ^ 1, kt + 1);

    short8 a[2][2], b[2][2];
#pragma unroll
    for (int fr = 0; fr < 2; ++fr) {
      a[fr][0] = *(const short8*)&As[buf][co0 + arow + fr * 256];
      a[fr][1] = *(const short8*)&As[buf][co1 + arow + fr * 256];
    }
#pragma unroll
    for (int fc = 0; fc < 2; ++fc) {
      b[fc][0] = *(const short8*)&Bs[buf][co0 + brow + fc * 256];
      b[fc][1] = *(const short8*)&Bs[buf][co1 + brow + fc * 256];
    }

#pragma unroll
    for (int sl = 0; sl < 2; ++sl)
#pragma unroll
      for (int fc = 0; fc < 2; ++fc)
#pragma unroll
        for (int fr = 0; fr < 2; ++fr)
          acc[fr][fc] = __builtin_amdgcn_mfma_f32_32x32x16_bf16(
              a[fr][sl], b[fc][sl], acc[fr][fc], 0, 0, 0);

    __syncthreads();   // staged kt+1 landed + guards buffer overwrite
  }
#undef STG

  // epilogue: C/D col=lane&31, row=(reg&3)+8*(reg>>2)+4*(lane>>5)
#pragma unroll
  for (int fc = 0; fc < 2; ++fc) {
    const long col = n0 + wc * 64 + fc * 32 + l31;
    const float bsv = bias ? bf2f(bias[col]) : 0.0f;
#pragma unroll
    for (int fr = 0; fr < 2; ++fr) {
      const floatx16 v = acc[fr][fc];
      const long rbase = m0 + wr * 64 + fr * 32 + 4 * (l >> 5);
#pragma unroll
      for (int r = 0; r < 16; ++r) {
        const long row = rbase + (r & 3) + 8 * (r >> 2);
        float x = v[r] + bsv;
        if (relu) x = fmaxf(x, 0.0f);
        C[row * N + col] = f2bf(x);
      }
    }
  }
}

// ---------------------------------------------------------------------------
// Fused causal attention. kq: [B,S,D] (k==q), vt: [B,H,64,S] (V^T per head),
// fr: bf16 [B*S]. scores = (q.k)*0.125*fr[i], mask j>=i, row 0 zeroed.
// ---------------------------------------------------------------------------
__global__ __launch_bounds__(256) void attn_kernel(
    const ushort_t* __restrict__ kq, const ushort_t* __restrict__ vt,
    const ushort_t* __restrict__ fr, ushort_t* __restrict__ ao)
{
  __shared__ __align__(16) ushort_t P[4][64 * 72];
  const int t = threadIdx.x;
  const int lane = t & 63;
  const int w4 = t >> 6;
  const int wq = blockIdx.y * 4 + w4;
  const int b = blockIdx.x >> 4;
  const int h = blockIdx.x & 15;
  const int la = lane & 15;
  const int lb = lane >> 4;
  const int i0 = wq * 64;
  const long kbase = ((long)b * Sq) * Dq + h * 64;
  const long vbase = ((long)(b * Hq + h)) * (64L * Sq);

  short8 qf[4][2];
#pragma unroll
  for (int mf = 0; mf < 4; ++mf)
#pragma unroll
    for (int tt = 0; tt < 2; ++tt)
      qf[mf][tt] = *(const short8*)&kq[kbase + (long)(i0 + mf * 16 + la) * Dq + tt * 32 + lb * 8];

  float frs[4][4];
#pragma unroll
  for (int mf = 0; mf < 4; ++mf)
#pragma unroll
    for (int r = 0; r < 4; ++r)
      frs[mf][r] = 0.125f * bf2f(fr[b * Sq + i0 + mf * 16 + lb * 4 + r]);

  const floatx4 z4 = {0.f, 0.f, 0.f, 0.f};
  floatx4 o[4][4];
  float mrun[4][4], lrun[4][4];
#pragma unroll
  for (int mf = 0; mf < 4; ++mf)
#pragma unroll
    for (int x = 0; x < 4; ++x) {
      o[mf][x] = z4;
      mrun[mf][x] = -1e30f;
      lrun[mf][x] = 0.0f;
    }

  for (int jt = 0; jt <= wq; ++jt) {
    const int j0 = jt * 64;
    floatx4 s[4][4];
#pragma unroll
    for (int mf = 0; mf < 4; ++mf)
#pragma unroll
      for (int jf = 0; jf < 4; ++jf) s[mf][jf] = z4;

#pragma unroll
    for (int tt = 0; tt < 2; ++tt) {
      short8 kf[4];
#pragma unroll
      for (int jf = 0; jf < 4; ++jf)
        kf[jf] = *(const short8*)&kq[kbase + (long)(j0 + jf * 16 + la) * Dq + tt * 32 + lb * 8];
#pragma unroll
      for (int mf = 0; mf < 4; ++mf)
#pragma unroll
        for (int jf = 0; jf < 4; ++jf)
          s[mf][jf] = __builtin_amdgcn_mfma_f32_16x16x32_bf16(qf[mf][tt], kf[jf], s[mf][jf], 0, 0, 0);
    }

    const bool diag = (jt == wq);
#pragma unroll
    for (int mf = 0; mf < 4; ++mf)
#pragma unroll
      for (int jf = 0; jf < 4; ++jf)
#pragma unroll
        for (int r = 0; r < 4; ++r) {
          float x = s[mf][jf][r] * frs[mf][r];
          if (diag && (j0 + jf * 16 + la) >= (i0 + mf * 16 + lb * 4 + r)) x = -1e30f;
          s[mf][jf][r] = x;
        }

#pragma unroll
    for (int mf = 0; mf < 4; ++mf)
#pragma unroll
      for (int r = 0; r < 4; ++r) {
        float pm = fmaxf(fmaxf(s[mf][0][r], s[mf][1][r]), fmaxf(s[mf][2][r], s[mf][3][r]));
        pm = fmaxf(pm, __shfl_xor(pm, 1));
        pm = fmaxf(pm, __shfl_xor(pm, 2));
        pm = fmaxf(pm, __shfl_xor(pm, 4));
        pm = fmaxf(pm, __shfl_xor(pm, 8));
        const float mo = mrun[mf][r];
        const float mn = fmaxf(mo, pm);
        const float sc = __expf(mo - mn);
        mrun[mf][r] = mn;
        float rs = 0.0f;
#pragma unroll
        for (int jf = 0; jf < 4; ++jf) {
          const float p = __expf(s[mf][jf][r] - mn);
          s[mf][jf][r] = p;
          rs += p;
        }
        rs += __shfl_xor(rs, 1);
        rs += __shfl_xor(rs, 2);
        rs += __shfl_xor(rs, 4);
        rs += __shfl_xor(rs, 8);
        lrun[mf][r] = lrun[mf][r] * sc + rs;
#pragma unroll
        for (int df = 0; df < 4; ++df) o[mf][df][r] *= sc;
      }

    // P tile is wave-private LDS; same-wave ds_write->ds_read, no barrier
#pragma unroll
    for (int mf = 0; mf < 4; ++mf)
#pragma unroll
      for (int jf = 0; jf < 4; ++jf)
#pragma unroll
        for (int r = 0; r < 4; ++r)
          P[w4][(mf * 16 + lb * 4 + r) * 72 + jf * 16 + la] = f2bf(s[mf][jf][r]);

#pragma unroll
    for (int tt = 0; tt < 2; ++tt) {
      short8 pf[4], vf[4];
#pragma unroll
      for (int mf = 0; mf < 4; ++mf)
        pf[mf] = *(const short8*)&P[w4][(mf * 16 + la) * 72 + tt * 32 + lb * 8];
#pragma unroll
      for (int df = 0; df < 4; ++df)
        vf[df] = *(const short8*)&vt[vbase + (long)(df * 16 + la) * Sq + j0 + tt * 32 + lb * 8];
#pragma unroll
      for (int mf = 0; mf < 4; ++mf)
#pragma unroll
        for (int df = 0; df < 4; ++df)
          o[mf][df] = __builtin_amdgcn_mfma_f32_16x16x32_bf16(pf[mf], vf[df], o[mf][df], 0, 0, 0);
    }
  }

#pragma unroll
  for (int mf = 0; mf < 4; ++mf)
#pragma unroll
    for (int df = 0; df < 4; ++df)
#pragma unroll
      for (int r = 0; r < 4; ++r) {
        const int ii = i0 + mf * 16 + lb * 4 + r;
        const float vv = (ii == 0) ? 0.0f : o[mf][df][r] / lrun[mf][r];
        ao[((long)b * Sq + ii) * Dq + h * 64 + df * 16 + la] = f2bf(vv);
      }
}

// ---------------------------------------------------------------------------
// Fused residual-add + LayerNorm. v = xf + add (+ add2 for split-K partial).
// final_==1: write d_out per flags[0] dtype.
// ---------------------------------------------------------------------------
__global__ __launch_bounds__(256) void ln_kernel(
    float* __restrict__ xf, const ushort_t* __restrict__ add,
    const ushort_t* __restrict__ add2,
    const ushort_t* __restrict__ g, const ushort_t* __restrict__ bb,
    ushort_t* __restrict__ outb, float* __restrict__ outf,
    const int* __restrict__ flags, int final_)
{
  __shared__ float red[2][4];
  const long row = blockIdx.x;
  const int t = threadIdx.x;
  const int c = t * 4;
  float* xr = xf + row * Dq;
  const ushort_t* ar = add + row * Dq;

  floatx4 xv = *(floatx4*)&xr[c];
  ushortx4 av = *(const ushortx4*)&ar[c];
  ushortx4 a2v;
  if (add2) a2v = *(const ushortx4*)&add2[row * Dq + c];
  float v[4];
  float s1 = 0.f, s2 = 0.f;
#pragma unroll
  for (int e = 0; e < 4; ++e) {
    float av_ = bf2f(av[e]);
    if (add2) av_ += bf2f(a2v[e]);
    v[e] = xv[e] + av_;
    s1 += v[e];
    s2 += v[e] * v[e];
  }
#pragma unroll
  for (int m = 1; m < 64; m <<= 1) {
    s1 += __shfl_xor(s1, m);
    s2 += __shfl_xor(s2, m);
  }
  const int lane = t & 63, w = t >> 6;
  if (lane == 0) { red[0][w] = s1; red[1][w] = s2; }
  __syncthreads();
  s1 = red[0][0] + red[0][1] + red[0][2] + red[0][3];
  s2 = red[1][0] + red[1][1] + red[1][2] + red[1][3];
  const float mean = s1 * (1.0f / Dq);
  const float var = fmaxf(s2 * (1.0f / Dq) - mean * mean, 0.0f);
  const float rstd = rsqrtf(var + 1e-5f);
  ushortx4 gv = *(const ushortx4*)&g[c];
  ushortx4 bv = *(const ushortx4*)&bb[c];
  ushortx4 ob;
  floatx4 xo;
#pragma unroll
  for (int e = 0; e < 4; ++e) {
    const float y = (v[e] - mean) * rstd * bf2f(gv[e]) + bf2f(bv[e]);
    xo[e] = y;
    ob[e] = f2bf(y);
  }
  *(floatx4*)&xr[c] = xo;
  if (final_ && !flags[0]) {
    *(floatx4*)&outf[row * Dq + c] = xo;
  } else {
    *(ushortx4*)&outb[row * Dq + c] = ob;
  }
}

// x = qe + pe (fp32 + bf16), y = qa + pe (bf16); flag-aware source dtype
__global__ __launch_bounds__(256) void addpe_kernel(
    const void* __restrict__ qe, const void* __restrict__ qa,
    const void* __restrict__ pe, float* __restrict__ xf,
    ushort_t* __restrict__ xb, ushort_t* __restrict__ yb,
    const int* __restrict__ flags)
{
  const long i = ((long)blockIdx.x * 256 + threadIdx.x) * 8;
  const long sd = i & ((long)Sq * Dq - 1);
  const bool isb = flags[0] != 0;
  float q[8], a[8], p[8];
  if (isb) {
    ushortx8 q8 = *(const ushortx8*)((const ushort_t*)qe + i);
    ushortx8 a8 = *(const ushortx8*)((const ushort_t*)qa + i);
    ushortx8 p8 = *(const ushortx8*)((const ushort_t*)pe + sd);
#pragma unroll
    for (int e = 0; e < 8; ++e) { q[e] = bf2f(q8[e]); a[e] = bf2f(a8[e]); p[e] = bf2f(p8[e]); }
  } else {
    const float* qp = (const float*)qe + i;
    const float* ap = (const float*)qa + i;
    const float* pp = (const float*)pe + sd;
    floatx4 q0 = *(const floatx4*)qp, q1 = *(const floatx4*)(qp + 4);
    floatx4 a0 = *(const floatx4*)ap, a1 = *(const floatx4*)(ap + 4);
    floatx4 p0 = *(const floatx4*)pp, p1 = *(const floatx4*)(pp + 4);
#pragma unroll
    for (int e = 0; e < 4; ++e) {
      q[e] = q0[e]; q[e + 4] = q1[e];
      a[e] = a0[e]; a[e + 4] = a1[e];
      p[e] = p0[e]; p[e + 4] = p1[e];
    }
  }
  ushortx8 xo, yo;
  floatx4 f0, f1;
#pragma unroll
  for (int e = 0; e < 8; ++e) {
    const float xvv = (isb ? q[e] : bf2f(f2bf(q[e]))) + (isb ? p[e] : bf2f(f2bf(p[e])));
    const float yvv = (isb ? a[e] : bf2f(f2bf(a[e]))) + (isb ? p[e] : bf2f(f2bf(p[e])));
    if (e < 4) { f0[e] = xvv; } else { f1[e - 4] = xvv; }
    xo[e] = f2bf(xvv);
    yo[e] = f2bf(yvv);
  }
  *(floatx4*)&xf[i] = f0;
  *(floatx4*)&xf[i + 4] = f1;
  *(ushortx8*)&xb[i] = xo;
  *(ushortx8*)&yb[i] = yo;
}

// dst[z][n][k] = src[z][k][n]; flag-aware source dtype (weights: flags[1])
__global__ __launch_bounds__(256) void transpose_kernel(
    const void* __restrict__ src, ushort_t* __restrict__ dst, int K, int N,
    const int* __restrict__ flags)
{
  __shared__ __align__(16) ushort_t tile[64][72];
  const bool isb = flags[1] != 0;
  const long base = (long)blockIdx.z * K * N;
  const int k0 = blockIdx.y * 64, n0 = blockIdx.x * 64;
  const int t = threadIdx.x;
  const int r = t >> 3;
  const int cc = (t & 7) << 3;
#pragma unroll
  for (int it = 0; it < 2; ++it) {
    const int rr = r + it * 32;
    const long gi = base + (long)(k0 + rr) * N + n0 + cc;
    if (isb) {
      *(short8*)&tile[rr][cc] = *(const short8*)((const ushort_t*)src + gi);
    } else {
      const float* sf = (const float*)src + gi;
      floatx4 v0 = *(const floatx4*)sf;
      floatx4 v1 = *(const floatx4*)(sf + 4);
#pragma unroll
      for (int e = 0; e < 4; ++e) {
        tile[rr][cc + e] = f2bf(v0[e]);
        tile[rr][cc + 4 + e] = f2bf(v1[e]);
      }
    }
  }
  __syncthreads();
#pragma unroll
  for (int it = 0; it < 2; ++it) {
    const int rr = r + it * 32;
    short8 v;
#pragma unroll
    for (int e = 0; e < 8; ++e) v[e] = (short)tile[cc + e][rr];
    *(short8*)&dst[base + (long)(n0 + rr) * K + k0 + cc] = v;
  }
}

// vt[b][h][d][j] = vb[b][j][h*64+d]  (vb is bf16 workspace, no flag needed)
__global__ __launch_bounds__(256) void vtrans_kernel(
    const ushort_t* __restrict__ vb, ushort_t* __restrict__ vt)
{
  __shared__ __align__(16) ushort_t tile[64][72];
  const int b = blockIdx.y >> 4, h = blockIdx.y & 15;
  const int j0 = blockIdx.x * 64;
  const int t = threadIdx.x;
  const int r = t >> 3;
  const int cc = (t & 7) << 3;
#pragma unroll
  for (int it = 0; it < 2; ++it) {
    const int rr = r + it * 32;
    *(short8*)&tile[rr][cc] = *(const short8*)&vb[((long)b * Sq + j0 + rr) * Dq + h * 64 + cc];
  }
  __syncthreads();
#pragma unroll
  for (int it = 0; it < 2; ++it) {
    const int rr = r + it * 32;
    short8 v;
#pragma unroll
    for (int e = 0; e < 8; ++e) v[e] = (short)tile[cc + e][rr];
    *(short8*)&vt[((long)(b * Hq + h) * 64 + rr) * Sq + j0 + cc] = v;
  }
}

extern "C" void kernel_launch(void* const* d_in, const int* in_sizes, int n_in,
                              void* d_out, int out_size, void* d_ws, size_t ws_size,
                              hipStream_t stream)
{
  if (n_in < 18) return;
  const void* qe  = d_in[0];
  const void* qa  = d_in[1];
  const void* fr  = d_in[2];
  const void* pe  = d_in[3];
  const void* Wk  = d_in[4];
  const void* bk  = d_in[5];
  const void* Wv  = d_in[6];
  const void* bv  = d_in[7];
  const void* Wo  = d_in[8];
  const void* bo  = d_in[9];
  const void* W1  = d_in[10];
  const void* b1  = d_in[11];
  const void* W2  = d_in[12];
  const void* b2  = d_in[13];
  const void* g1  = d_in[14];
  const void* be1 = d_in[15];
  const void* g2  = d_in[16];
  const void* be2 = d_in[17];

  char* ws = (char*)d_ws;
  const size_t SM = 243269632L;
  const size_t NEED = SM + 114752L;
  if (ws_size < NEED) return;

  float*    xf   = (float*)   (ws + 0L);
  ushort_t* xb   = (ushort_t*)(ws + 33554432L);
  ushort_t* yb   = (ushort_t*)(ws + 50331648L);
  ushort_t* tmpD = (ushort_t*)(ws + 67108864L);
  ushort_t* WkT  = (ushort_t*)(ws + 83886080L);
  ushort_t* WvT  = (ushort_t*)(ws + 92274688L);
  ushort_t* WoT  = (ushort_t*)(ws + 100663296L);
  ushort_t* W1T  = (ushort_t*)(ws + 109051904L);
  ushort_t* W2T  = (ushort_t*)(ws + 142606336L);
  ushort_t* kb   = (ushort_t*)(ws + 176160768L);
  ushort_t* vbf  = (ushort_t*)(ws + 192937984L);
  ushort_t* vtb  = (ushort_t*)(ws + 209715200L);
  ushort_t* ff1  = kb;  // 64 MiB region, disjoint lifetime

  int*      flags = (int*)(ws + SM);
  ushort_t* frc  = (ushort_t*)(ws + SM + 64);
  ushort_t* bkc  = (ushort_t*)(ws + SM + 16448);
  ushort_t* bvc  = (ushort_t*)(ws + SM + 24640);
  ushort_t* boc  = (ushort_t*)(ws + SM + 32832);
  ushort_t* b1c  = (ushort_t*)(ws + SM + 41024);
  ushort_t* b2c  = (ushort_t*)(ws + SM + 73792);
  ushort_t* g1c  = (ushort_t*)(ws + SM + 81984);
  ushort_t* be1c = (ushort_t*)(ws + SM + 90176);
  ushort_t* g2c  = (ushort_t*)(ws + SM + 98368);
  ushort_t* be2c = (ushort_t*)(ws + SM + 106560);

  probe_kernel<<<1, 64, 0, stream>>>((const ushort_t*)pe, (const ushort_t*)g1, flags);

  {
    CvtArgs a;
    const void* srcs[10] = {fr, bk, bv, bo, b1, b2, g1, be1, g2, be2};
    ushort_t*   dsts[10] = {frc, bkc, bvc, boc, b1c, b2c, g1c, be1c, g2c, be2c};
    const int   ns[10]   = {8192, 4096, 4096, 4096, 16384, 4096, 4096, 4096, 4096, 4096};
    int cum = 0;
    for (int s = 0; s < 10; ++s) {
      a.src[s] = srcs[s]; a.dst[s] = dsts[s]; a.n[s] = ns[s];
      a.fi[s] = (s == 0) ? 0 : 1;
      a.cum[s] = cum;
      cum += (ns[s] + 255) / 256;
    }
    a.cum[10] = cum;
    convert_all_kernel<<<cum, 256, 0, stream>>>(a, flags);
  }

  transpose_kernel<<<dim3(16, 16, 4), 256, 0, stream>>>(Wk, WkT, 1024, 1024, flags);
  transpose_kernel<<<dim3(16, 16, 4), 256, 0, stream>>>(Wv, WvT, 1024, 1024, flags);
  transpose_kernel<<<dim3(16, 16, 4), 256, 0, stream>>>(Wo, WoT, 1024, 1024, flags);
  transpose_kernel<<<dim3(64, 16, 4), 256, 0, stream>>>(W1, W1T, 1024, 4096, flags);
  transpose_kernel<<<dim3(16, 64, 4), 256, 0, stream>>>(W2, W2T, 4096, 1024, flags);

  addpe_kernel<<<4096, 256, 0, stream>>>(qe, qa, pe, xf, xb, yb, flags);

  for (int l = 0; l < 4; ++l) {
    // K-proj (z=0) + V-proj (z=1): 1024 blocks -> 4 blocks/CU
    gemm128_kernel<<<dim3(8, 64, 2), 256, 0, stream>>>(
        xb, WkT + (long)l * 1048576, bkc + l * 1024, kb, 0,
        yb, WvT + (long)l * 1048576, bvc + l * 1024, vbf, 0,
        1024, 1024, 1024, 0);
    vtrans_kernel<<<dim3(8, 256), 256, 0, stream>>>(vbf, vtb);
    attn_kernel<<<dim3(256, 2), 256, 0, stream>>>(kb, vtb, frc, vbf);  // ao aliases vbf
    // Wo: split-K=2 (xb is dead here) -> 1024 blocks
    gemm128_kernel<<<dim3(8, 64, 2), 256, 0, stream>>>(
        vbf, WoT + (long)l * 1048576, boc + l * 1024, tmpD, 0,
        vbf, WoT + (long)l * 1048576, nullptr,        xb,   512,
        1024, 1024, 512, 0);
    ln_kernel<<<8192, 256, 0, stream>>>(xf, tmpD, xb, g1c + l * 1024, be1c + l * 1024,
                                        xb, nullptr, flags, 0);
    // FF1: 2048 blocks
    gemm128_kernel<<<dim3(32, 64, 1), 256, 0, stream>>>(
        xb, W1T + (long)l * 4194304, b1c + l * 4096, ff1, 0,
        xb, W1T + (long)l * 4194304, b1c + l * 4096, ff1, 0,
        4096, 1024, 1024, 1);
    // FF2: split-K=2 (xb dead after FF1) -> 1024 blocks
    gemm128_kernel<<<dim3(8, 64, 2), 256, 0, stream>>>(
        ff1, W2T + (long)l * 4194304, b2c + l * 1024, tmpD, 0,
        ff1, W2T + (long)l * 4194304, nullptr,        xb,   2048,
        1024, 4096, 2048, 0);
    if (l == 3) {
      ln_kernel<<<8192, 256, 0, stream>>>(xf, tmpD, xb, g2c + l * 1024, be2c + l * 1024,
                                          (ushort_t*)d_out, (float*)d_out, flags, 1);
    } else {
      ln_kernel<<<8192, 256, 0, stream>>>(xf, tmpD, xb, g2c + l * 1024, be2c + l * 1024,
                                          xb, nullptr, flags, 0);
    }
  }
}

// Round 12
// 1623.741 us; speedup vs baseline: 1.3840x; 1.3840x over previous
//
#include <hip/hip_runtime.h>
#include <hip/hip_bf16.h>
#include <cstdint>
#include <cstddef>

// Problem constants
#define Bq 16
#define Sq 512
#define Dq 1024
#define Hq 16
#define Lq 4
#define FFq 4096
#define Mq (Bq * Sq)  // 8192

typedef unsigned short ushort_t;
typedef __attribute__((ext_vector_type(8))) short short8;
typedef __attribute__((ext_vector_type(8))) unsigned short ushortx8;
typedef __attribute__((ext_vector_type(4))) unsigned short ushortx4;
typedef __attribute__((ext_vector_type(4))) float floatx4;
typedef __attribute__((ext_vector_type(16))) float floatx16;

__device__ __forceinline__ float bf2f(ushort_t u) {
  union { unsigned int i; float f; } x;
  x.i = ((unsigned int)u) << 16;
  return x.f;
}
__device__ __forceinline__ ushort_t f2bf(float f) {
  unsigned int u = __float_as_uint(f);
  u += 0x7fffu + ((u >> 16) & 1u);
  return (ushort_t)(u >> 16);
}

// async global->LDS, 16B per lane; LDS dest is wave-uniform base + lane*16
#define GLL16(gp, lp) __builtin_amdgcn_global_load_lds( \
    (__attribute__((address_space(1))) void*)(gp),      \
    (__attribute__((address_space(3))) void*)(lp), 16, 0, 0)

template<int N> __device__ __forceinline__ void waitvm() {
  if constexpr (N == 0)       asm volatile("s_waitcnt vmcnt(0)" ::: "memory");
  else if constexpr (N == 6)  asm volatile("s_waitcnt vmcnt(6)" ::: "memory");
  else                        asm volatile("s_waitcnt vmcnt(12)" ::: "memory");
}

// ---------------------------------------------------------------------------
// dtype probe: pe[1] (= cos(0) = 1.0) and ln1_g[0] (= 1.0).
// ---------------------------------------------------------------------------
__global__ void probe_kernel(const ushort_t* __restrict__ pe,
                             const ushort_t* __restrict__ g1,
                             int* __restrict__ flags)
{
  if (threadIdx.x == 0 && blockIdx.x == 0) {
    flags[0] = (pe[1] == (ushort_t)0x3F80u) ? 1 : 0;
    flags[1] = (g1[0] == (ushort_t)0x3F80u) ? 1 : 0;
  }
}

// fused small-tensor canonicalize: 10 segments in one dispatch
struct CvtArgs {
  const void* src[10];
  ushort_t*   dst[10];
  int         n[10];
  int         fi[10];
  int         cum[11];
};
__global__ __launch_bounds__(256) void convert_all_kernel(
    CvtArgs a, const int* __restrict__ flags)
{
  const int bidx = blockIdx.x;
  int s = 0;
  while (s < 9 && bidx >= a.cum[s + 1]) ++s;
  const int i = (bidx - a.cum[s]) * 256 + threadIdx.x;
  if (i >= a.n[s]) return;
  if (flags[a.fi[s]]) a.dst[s][i] = ((const ushort_t*)a.src[s])[i];
  else                a.dst[s][i] = f2bf(((const float*)a.src[s])[i]);
}

// ---------------------------------------------------------------------------
// 256x128 / 32x32x16-MFMA GEMM, wave = 128x64 (FR=4, FC=2), split-K capable.
// r11 lesson: granule-major LDS broke global coalescing (-55%); reverted to
// r10's row-major + source-swizzle staging (64B-contiguous segments, r9/r10
// numerics verified). Model (fits r10 29% and m201 62%): util ~ MFMA_cyc /
// (MFMA + LDS_read + LDS_write) at ~512 B/cyc/CU -> wave 128x64 gives
// reads 24KB + writes 24KB vs MFMA 129cy -> ceiling ~58% (r10 64x64: 40%).
// 3-buffer counted-vmcnt pipeline (r4-proven) hides load latency at the
// 2-blocks/CU residency this 72KB-LDS config allows.
// C/D layout (m74/m101): col=lane&31, row=(reg&3)+8*(reg>>2)+4*(lane>>5).
// blockIdx.z picks pointer set (op batching / split-K partials).
// ---------------------------------------------------------------------------
__global__ __launch_bounds__(256, 2) void gemm256_kernel(
    const ushort_t* __restrict__ A0, const ushort_t* __restrict__ BT0,
    const ushort_t* __restrict__ bias0, ushort_t* __restrict__ C0, int koff0,
    const ushort_t* __restrict__ A1, const ushort_t* __restrict__ BT1,
    const ushort_t* __restrict__ bias1, ushort_t* __restrict__ C1, int koff1,
    int N, int Kst, int Klen, int relu)
{
  __shared__ __align__(16) ushort_t As[3][256 * 32];  // 48 KB
  __shared__ __align__(16) ushort_t Bs[3][128 * 32];  // 24 KB

  const ushort_t* A    = blockIdx.z ? A1 : A0;
  const ushort_t* BT   = blockIdx.z ? BT1 : BT0;
  const ushort_t* bias = blockIdx.z ? bias1 : bias0;
  ushort_t*       C    = blockIdx.z ? C1 : C0;
  const int       koff = blockIdx.z ? koff1 : koff0;

  const int t = threadIdx.x;
  const int l = t & 63;
  const int wid = t >> 6;
  const int l31 = l & 31;
  const int wr = wid >> 1;   // wave M-half (rows 128 each)
  const int wc = wid & 1;    // wave N-half (cols 64 each)

  // ---- T1 XCD slab swizzle (bijective; gy = 32, multiple of 8) ----
  int bx = blockIdx.x, by = blockIdx.y;
  {
    const int gx = gridDim.x, gy = gridDim.y;
    if ((gy & 7) == 0) {
      const int orig = by * gx + bx;
      const int xcd = orig & 7;
      const int local = orig >> 3;
      const int rows = gy >> 3;
      by = xcd * rows + local % rows;
      bx = local / rows;
    }
  }
  const long m0 = (long)by * 256;
  const long n0 = (long)bx * 128;
  const int nk = Klen >> 5;

  // staging (r10-proven): thread t covers row t>>2, granule t&3 per 64-row
  // chunk; T2 inverse swizzle on SOURCE column; LDS stays linear.
  const int srow = t >> 2;
  const int scol = (((t & 3) ^ ((srow >> 1) & 3)) << 3);
  const ushort_t* sA = A + (m0 + srow) * (long)Kst + koff + scol;
  const ushort_t* sB = BT + (n0 + srow) * (long)Kst + koff + scol;
  const long rs64 = 64L * (long)Kst;
  const int lws = wid * 512;   // wave-uniform LDS elem base within a chunk

#define STG(buf_, kt_) do {                                            \
    const long ko_ = (long)(kt_) << 5;                                 \
    GLL16(sA + ko_,            &As[(buf_)][lws]);                      \
    GLL16(sA + rs64 + ko_,     &As[(buf_)][2048 + lws]);               \
    GLL16(sA + 2 * rs64 + ko_, &As[(buf_)][4096 + lws]);               \
    GLL16(sA + 3 * rs64 + ko_, &As[(buf_)][6144 + lws]);               \
    GLL16(sB + ko_,            &Bs[(buf_)][lws]);                      \
    GLL16(sB + rs64 + ko_,     &Bs[(buf_)][2048 + lws]);               \
  } while (0)

  floatx16 acc[4][2];
#pragma unroll
  for (int i = 0; i < 4; ++i)
#pragma unroll
    for (int j = 0; j < 2; ++j)
#pragma unroll
      for (int r = 0; r < 16; ++r) acc[i][j][r] = 0.0f;

  // frag-read swizzled column offsets (r9-verified): granule = sl*2+(l>>5),
  // XOR'd with row bits ((l>>1)&3 == (row>>1)&3 for all frag rows).
  const int xo = (l >> 1) & 3;
  const int co0 = (((l >> 5)) ^ xo) << 3;       // k-slice 0
  const int co1 = ((2 + (l >> 5)) ^ xo) << 3;   // k-slice 1
  const int arow = wr * 128 + l31;              // + fr*32
  const int brow = wc * 64 + l31;               // + fc*32

  // prologue: 2 tiles staged ahead
  STG(0, 0);
  if (nk > 1) STG(1, 1);

  for (int kt = 0; kt < nk; ++kt) {
    const int buf = kt % 3;
    // stage kt+2 into buf (kt+2)%3 (freed at end of iter kt-1)
    if (kt + 2 < nk) { STG((kt + 2) % 3, kt + 2); waitvm<12>(); }
    else if (kt + 1 < nk) waitvm<6>();
    else waitvm<0>();
    __builtin_amdgcn_s_barrier();          // tile kt visible to all waves
    __builtin_amdgcn_sched_barrier(0);

    short8 a[4][2], b[2][2];
#pragma unroll
    for (int fr = 0; fr < 4; ++fr) {
      a[fr][0] = *(const short8*)&As[buf][(arow + fr * 32) * 32 + co0];
      a[fr][1] = *(const short8*)&As[buf][(arow + fr * 32) * 32 + co1];
    }
#pragma unroll
    for (int fc = 0; fc < 2; ++fc) {
      b[fc][0] = *(const short8*)&Bs[buf][(brow + fc * 32) * 32 + co0];
      b[fc][1] = *(const short8*)&Bs[buf][(brow + fc * 32) * 32 + co1];
    }

#pragma unroll
    for (int sl = 0; sl < 2; ++sl)
#pragma unroll
      for (int fc = 0; fc < 2; ++fc)
#pragma unroll
        for (int fr = 0; fr < 4; ++fr)
          acc[fr][fc] = __builtin_amdgcn_mfma_f32_32x32x16_bf16(
              a[fr][sl], b[fc][sl], acc[fr][fc], 0, 0, 0);

    __builtin_amdgcn_s_barrier();          // reads of buf done before restage
  }
#undef STG

  // epilogue: C/D col=lane&31, row=(reg&3)+8*(reg>>2)+4*(lane>>5)
#pragma unroll
  for (int fc = 0; fc < 2; ++fc) {
    const long col = n0 + wc * 64 + fc * 32 + l31;
    const float bsv = bias ? bf2f(bias[col]) : 0.0f;
#pragma unroll
    for (int fr = 0; fr < 4; ++fr) {
      const floatx16 v = acc[fr][fc];
      const long rbase = m0 + wr * 128 + fr * 32 + 4 * (l >> 5);
#pragma unroll
      for (int r = 0; r < 16; ++r) {
        const long row = rbase + (r & 3) + 8 * (r >> 2);
        float x = v[r] + bsv;
        if (relu) x = fmaxf(x, 0.0f);
        C[row * N + col] = f2bf(x);
      }
    }
  }
}

// ---------------------------------------------------------------------------
// Fused causal attention. kq: [B,S,D] (k==q), vt: [B,H,64,S] (V^T per head),
// fr: bf16 [B*S]. scores = (q.k)*0.125*fr[i], mask j>=i, row 0 zeroed.
// ---------------------------------------------------------------------------
__global__ __launch_bounds__(256) void attn_kernel(
    const ushort_t* __restrict__ kq, const ushort_t* __restrict__ vt,
    const ushort_t* __restrict__ fr, ushort_t* __restrict__ ao)
{
  __shared__ __align__(16) ushort_t P[4][64 * 72];
  const int t = threadIdx.x;
  const int lane = t & 63;
  const int w4 = t >> 6;
  const int wq = blockIdx.y * 4 + w4;
  const int b = blockIdx.x >> 4;
  const int h = blockIdx.x & 15;
  const int la = lane & 15;
  const int lb = lane >> 4;
  const int i0 = wq * 64;
  const long kbase = ((long)b * Sq) * Dq + h * 64;
  const long vbase = ((long)(b * Hq + h)) * (64L * Sq);

  short8 qf[4][2];
#pragma unroll
  for (int mf = 0; mf < 4; ++mf)
#pragma unroll
    for (int tt = 0; tt < 2; ++tt)
      qf[mf][tt] = *(const short8*)&kq[kbase + (long)(i0 + mf * 16 + la) * Dq + tt * 32 + lb * 8];

  float frs[4][4];
#pragma unroll
  for (int mf = 0; mf < 4; ++mf)
#pragma unroll
    for (int r = 0; r < 4; ++r)
      frs[mf][r] = 0.125f * bf2f(fr[b * Sq + i0 + mf * 16 + lb * 4 + r]);

  const floatx4 z4 = {0.f, 0.f, 0.f, 0.f};
  floatx4 o[4][4];
  float mrun[4][4], lrun[4][4];
#pragma unroll
  for (int mf = 0; mf < 4; ++mf)
#pragma unroll
    for (int x = 0; x < 4; ++x) {
      o[mf][x] = z4;
      mrun[mf][x] = -1e30f;
      lrun[mf][x] = 0.0f;
    }

  for (int jt = 0; jt <= wq; ++jt) {
    const int j0 = jt * 64;
    floatx4 s[4][4];
#pragma unroll
    for (int mf = 0; mf < 4; ++mf)
#pragma unroll
      for (int jf = 0; jf < 4; ++jf) s[mf][jf] = z4;

#pragma unroll
    for (int tt = 0; tt < 2; ++tt) {
      short8 kf[4];
#pragma unroll
      for (int jf = 0; jf < 4; ++jf)
        kf[jf] = *(const short8*)&kq[kbase + (long)(j0 + jf * 16 + la) * Dq + tt * 32 + lb * 8];
#pragma unroll
      for (int mf = 0; mf < 4; ++mf)
#pragma unroll
        for (int jf = 0; jf < 4; ++jf)
          s[mf][jf] = __builtin_amdgcn_mfma_f32_16x16x32_bf16(qf[mf][tt], kf[jf], s[mf][jf], 0, 0, 0);
    }

    const bool diag = (jt == wq);
#pragma unroll
    for (int mf = 0; mf < 4; ++mf)
#pragma unroll
      for (int jf = 0; jf < 4; ++jf)
#pragma unroll
        for (int r = 0; r < 4; ++r) {
          float x = s[mf][jf][r] * frs[mf][r];
          if (diag && (j0 + jf * 16 + la) >= (i0 + mf * 16 + lb * 4 + r)) x = -1e30f;
          s[mf][jf][r] = x;
        }

#pragma unroll
    for (int mf = 0; mf < 4; ++mf)
#pragma unroll
      for (int r = 0; r < 4; ++r) {
        float pm = fmaxf(fmaxf(s[mf][0][r], s[mf][1][r]), fmaxf(s[mf][2][r], s[mf][3][r]));
        pm = fmaxf(pm, __shfl_xor(pm, 1));
        pm = fmaxf(pm, __shfl_xor(pm, 2));
        pm = fmaxf(pm, __shfl_xor(pm, 4));
        pm = fmaxf(pm, __shfl_xor(pm, 8));
        const float mo = mrun[mf][r];
        const float mn = fmaxf(mo, pm);
        const float sc = __expf(mo - mn);
        mrun[mf][r] = mn;
        float rs = 0.0f;
#pragma unroll
        for (int jf = 0; jf < 4; ++jf) {
          const float p = __expf(s[mf][jf][r] - mn);
          s[mf][jf][r] = p;
          rs += p;
        }
        rs += __shfl_xor(rs, 1);
        rs += __shfl_xor(rs, 2);
        rs += __shfl_xor(rs, 4);
        rs += __shfl_xor(rs, 8);
        lrun[mf][r] = lrun[mf][r] * sc + rs;
#pragma unroll
        for (int df = 0; df < 4; ++df) o[mf][df][r] *= sc;
      }

    // P tile is wave-private LDS; same-wave ds_write->ds_read, no barrier
#pragma unroll
    for (int mf = 0; mf < 4; ++mf)
#pragma unroll
      for (int jf = 0; jf < 4; ++jf)
#pragma unroll
        for (int r = 0; r < 4; ++r)
          P[w4][(mf * 16 + lb * 4 + r) * 72 + jf * 16 + la] = f2bf(s[mf][jf][r]);

#pragma unroll
    for (int tt = 0; tt < 2; ++tt) {
      short8 pf[4], vf[4];
#pragma unroll
      for (int mf = 0; mf < 4; ++mf)
        pf[mf] = *(const short8*)&P[w4][(mf * 16 + la) * 72 + tt * 32 + lb * 8];
#pragma unroll
      for (int df = 0; df < 4; ++df)
        vf[df] = *(const short8*)&vt[vbase + (long)(df * 16 + la) * Sq + j0 + tt * 32 + lb * 8];
#pragma unroll
      for (int mf = 0; mf < 4; ++mf)
#pragma unroll
        for (int df = 0; df < 4; ++df)
          o[mf][df] = __builtin_amdgcn_mfma_f32_16x16x32_bf16(pf[mf], vf[df], o[mf][df], 0, 0, 0);
    }
  }

#pragma unroll
  for (int mf = 0; mf < 4; ++mf)
#pragma unroll
    for (int df = 0; df < 4; ++df)
#pragma unroll
      for (int r = 0; r < 4; ++r) {
        const int ii = i0 + mf * 16 + lb * 4 + r;
        const float vv = (ii == 0) ? 0.0f : o[mf][df][r] / lrun[mf][r];
        ao[((long)b * Sq + ii) * Dq + h * 64 + df * 16 + la] = f2bf(vv);
      }
}

// ---------------------------------------------------------------------------
// Fused residual-add + LayerNorm. v = xf + add (+ add2 for split-K partial).
// final_==1: write d_out per flags[0] dtype.
// ---------------------------------------------------------------------------
__global__ __launch_bounds__(256) void ln_kernel(
    float* __restrict__ xf, const ushort_t* __restrict__ add,
    const ushort_t* __restrict__ add2,
    const ushort_t* __restrict__ g, const ushort_t* __restrict__ bb,
    ushort_t* __restrict__ outb, float* __restrict__ outf,
    const int* __restrict__ flags, int final_)
{
  __shared__ float red[2][4];
  const long row = blockIdx.x;
  const int t = threadIdx.x;
  const int c = t * 4;
  float* xr = xf + row * Dq;
  const ushort_t* ar = add + row * Dq;

  floatx4 xv = *(floatx4*)&xr[c];
  ushortx4 av = *(const ushortx4*)&ar[c];
  ushortx4 a2v;
  if (add2) a2v = *(const ushortx4*)&add2[row * Dq + c];
  float v[4];
  float s1 = 0.f, s2 = 0.f;
#pragma unroll
  for (int e = 0; e < 4; ++e) {
    float av_ = bf2f(av[e]);
    if (add2) av_ += bf2f(a2v[e]);
    v[e] = xv[e] + av_;
    s1 += v[e];
    s2 += v[e] * v[e];
  }
#pragma unroll
  for (int m = 1; m < 64; m <<= 1) {
    s1 += __shfl_xor(s1, m);
    s2 += __shfl_xor(s2, m);
  }
  const int lane = t & 63, w = t >> 6;
  if (lane == 0) { red[0][w] = s1; red[1][w] = s2; }
  __syncthreads();
  s1 = red[0][0] + red[0][1] + red[0][2] + red[0][3];
  s2 = red[1][0] + red[1][1] + red[1][2] + red[1][3];
  const float mean = s1 * (1.0f / Dq);
  const float var = fmaxf(s2 * (1.0f / Dq) - mean * mean, 0.0f);
  const float rstd = rsqrtf(var + 1e-5f);
  ushortx4 gv = *(const ushortx4*)&g[c];
  ushortx4 bv = *(const ushortx4*)&bb[c];
  ushortx4 ob;
  floatx4 xo;
#pragma unroll
  for (int e = 0; e < 4; ++e) {
    const float y = (v[e] - mean) * rstd * bf2f(gv[e]) + bf2f(bv[e]);
    xo[e] = y;
    ob[e] = f2bf(y);
  }
  *(floatx4*)&xr[c] = xo;
  if (final_ && !flags[0]) {
    *(floatx4*)&outf[row * Dq + c] = xo;
  } else {
    *(ushortx4*)&outb[row * Dq + c] = ob;
  }
}

// x = qe + pe (fp32 + bf16), y = qa + pe (bf16); flag-aware source dtype
__global__ __launch_bounds__(256) void addpe_kernel(
    const void* __restrict__ qe, const void* __restrict__ qa,
    const void* __restrict__ pe, float* __restrict__ xf,
    ushort_t* __restrict__ xb, ushort_t* __restrict__ yb,
    const int* __restrict__ flags)
{
  const long i = ((long)blockIdx.x * 256 + threadIdx.x) * 8;
  const long sd = i & ((long)Sq * Dq - 1);
  const bool isb = flags[0] != 0;
  float q[8], a[8], p[8];
  if (isb) {
    ushortx8 q8 = *(const ushortx8*)((const ushort_t*)qe + i);
    ushortx8 a8 = *(const ushortx8*)((const ushort_t*)qa + i);
    ushortx8 p8 = *(const ushortx8*)((const ushort_t*)pe + sd);
#pragma unroll
    for (int e = 0; e < 8; ++e) { q[e] = bf2f(q8[e]); a[e] = bf2f(a8[e]); p[e] = bf2f(p8[e]); }
  } else {
    const float* qp = (const float*)qe + i;
    const float* ap = (const float*)qa + i;
    const float* pp = (const float*)pe + sd;
    floatx4 q0 = *(const floatx4*)qp, q1 = *(const floatx4*)(qp + 4);
    floatx4 a0 = *(const floatx4*)ap, a1 = *(const floatx4*)(ap + 4);
    floatx4 p0 = *(const floatx4*)pp, p1 = *(const floatx4*)(pp + 4);
#pragma unroll
    for (int e = 0; e < 4; ++e) {
      q[e] = q0[e]; q[e + 4] = q1[e];
      a[e] = a0[e]; a[e + 4] = a1[e];
      p[e] = p0[e]; p[e + 4] = p1[e];
    }
  }
  ushortx8 xo, yo;
  floatx4 f0, f1;
#pragma unroll
  for (int e = 0; e < 8; ++e) {
    const float xvv = (isb ? q[e] : bf2f(f2bf(q[e]))) + (isb ? p[e] : bf2f(f2bf(p[e])));
    const float yvv = (isb ? a[e] : bf2f(f2bf(a[e]))) + (isb ? p[e] : bf2f(f2bf(p[e])));
    if (e < 4) { f0[e] = xvv; } else { f1[e - 4] = xvv; }
    xo[e] = f2bf(xvv);
    yo[e] = f2bf(yvv);
  }
  *(floatx4*)&xf[i] = f0;
  *(floatx4*)&xf[i + 4] = f1;
  *(ushortx8*)&xb[i] = xo;
  *(ushortx8*)&yb[i] = yo;
}

// dst[z][n][k] = src[z][k][n]; flag-aware source dtype (weights: flags[1])
__global__ __launch_bounds__(256) void transpose_kernel(
    const void* __restrict__ src, ushort_t* __restrict__ dst, int K, int N,
    const int* __restrict__ flags)
{
  __shared__ __align__(16) ushort_t tile[64][72];
  const bool isb = flags[1] != 0;
  const long base = (long)blockIdx.z * K * N;
  const int k0 = blockIdx.y * 64, n0 = blockIdx.x * 64;
  const int t = threadIdx.x;
  const int r = t >> 3;
  const int cc = (t & 7) << 3;
#pragma unroll
  for (int it = 0; it < 2; ++it) {
    const int rr = r + it * 32;
    const long gi = base + (long)(k0 + rr) * N + n0 + cc;
    if (isb) {
      *(short8*)&tile[rr][cc] = *(const short8*)((const ushort_t*)src + gi);
    } else {
      const float* sf = (const float*)src + gi;
      floatx4 v0 = *(const floatx4*)sf;
      floatx4 v1 = *(const floatx4*)(sf + 4);
#pragma unroll
      for (int e = 0; e < 4; ++e) {
        tile[rr][cc + e] = f2bf(v0[e]);
        tile[rr][cc + 4 + e] = f2bf(v1[e]);
      }
    }
  }
  __syncthreads();
#pragma unroll
  for (int it = 0; it < 2; ++it) {
    const int rr = r + it * 32;
    short8 v;
#pragma unroll
    for (int e = 0; e < 8; ++e) v[e] = (short)tile[cc + e][rr];
    *(short8*)&dst[base + (long)(n0 + rr) * K + k0 + cc] = v;
  }
}

// vt[b][h][d][j] = vb[b][j][h*64+d]  (vb is bf16 workspace, no flag needed)
__global__ __launch_bounds__(256) void vtrans_kernel(
    const ushort_t* __restrict__ vb, ushort_t* __restrict__ vt)
{
  __shared__ __align__(16) ushort_t tile[64][72];
  const int b = blockIdx.y >> 4, h = blockIdx.y & 15;
  const int j0 = blockIdx.x * 64;
  const int t = threadIdx.x;
  const int r = t >> 3;
  const int cc = (t & 7) << 3;
#pragma unroll
  for (int it = 0; it < 2; ++it) {
    const int rr = r + it * 32;
    *(short8*)&tile[rr][cc] = *(const short8*)&vb[((long)b * Sq + j0 + rr) * Dq + h * 64 + cc];
  }
  __syncthreads();
#pragma unroll
  for (int it = 0; it < 2; ++it) {
    const int rr = r + it * 32;
    short8 v;
#pragma unroll
    for (int e = 0; e < 8; ++e) v[e] = (short)tile[cc + e][rr];
    *(short8*)&vt[((long)(b * Hq + h) * 64 + rr) * Sq + j0 + cc] = v;
  }
}

extern "C" void kernel_launch(void* const* d_in, const int* in_sizes, int n_in,
                              void* d_out, int out_size, void* d_ws, size_t ws_size,
                              hipStream_t stream)
{
  if (n_in < 18) return;
  const void* qe  = d_in[0];
  const void* qa  = d_in[1];
  const void* fr  = d_in[2];
  const void* pe  = d_in[3];
  const void* Wk  = d_in[4];
  const void* bk  = d_in[5];
  const void* Wv  = d_in[6];
  const void* bv  = d_in[7];
  const void* Wo  = d_in[8];
  const void* bo  = d_in[9];
  const void* W1  = d_in[10];
  const void* b1  = d_in[11];
  const void* W2  = d_in[12];
  const void* b2  = d_in[13];
  const void* g1  = d_in[14];
  const void* be1 = d_in[15];
  const void* g2  = d_in[16];
  const void* be2 = d_in[17];

  char* ws = (char*)d_ws;
  const size_t SM = 243269632L;
  const size_t NEED = SM + 114752L;
  if (ws_size < NEED) return;

  float*    xf   = (float*)   (ws + 0L);
  ushort_t* xb   = (ushort_t*)(ws + 33554432L);
  ushort_t* yb   = (ushort_t*)(ws + 50331648L);
  ushort_t* tmpD = (ushort_t*)(ws + 67108864L);
  ushort_t* WkT  = (ushort_t*)(ws + 83886080L);
  ushort_t* WvT  = (ushort_t*)(ws + 92274688L);
  ushort_t* WoT  = (ushort_t*)(ws + 100663296L);
  ushort_t* W1T  = (ushort_t*)(ws + 109051904L);
  ushort_t* W2T  = (ushort_t*)(ws + 142606336L);
  ushort_t* kb   = (ushort_t*)(ws + 176160768L);
  ushort_t* vbf  = (ushort_t*)(ws + 192937984L);
  ushort_t* vtb  = (ushort_t*)(ws + 209715200L);
  ushort_t* ff1  = kb;  // 64 MiB region, disjoint lifetime

  int*      flags = (int*)(ws + SM);
  ushort_t* frc  = (ushort_t*)(ws + SM + 64);
  ushort_t* bkc  = (ushort_t*)(ws + SM + 16448);
  ushort_t* bvc  = (ushort_t*)(ws + SM + 24640);
  ushort_t* boc  = (ushort_t*)(ws + SM + 32832);
  ushort_t* b1c  = (ushort_t*)(ws + SM + 41024);
  ushort_t* b2c  = (ushort_t*)(ws + SM + 73792);
  ushort_t* g1c  = (ushort_t*)(ws + SM + 81984);
  ushort_t* be1c = (ushort_t*)(ws + SM + 90176);
  ushort_t* g2c  = (ushort_t*)(ws + SM + 98368);
  ushort_t* be2c = (ushort_t*)(ws + SM + 106560);

  probe_kernel<<<1, 64, 0, stream>>>((const ushort_t*)pe, (const ushort_t*)g1, flags);

  {
    CvtArgs a;
    const void* srcs[10] = {fr, bk, bv, bo, b1, b2, g1, be1, g2, be2};
    ushort_t*   dsts[10] = {frc, bkc, bvc, boc, b1c, b2c, g1c, be1c, g2c, be2c};
    const int   ns[10]   = {8192, 4096, 4096, 4096, 16384, 4096, 4096, 4096, 4096, 4096};
    int cum = 0;
    for (int s = 0; s < 10; ++s) {
      a.src[s] = srcs[s]; a.dst[s] = dsts[s]; a.n[s] = ns[s];
      a.fi[s] = (s == 0) ? 0 : 1;
      a.cum[s] = cum;
      cum += (ns[s] + 255) / 256;
    }
    a.cum[10] = cum;
    convert_all_kernel<<<cum, 256, 0, stream>>>(a, flags);
  }

  transpose_kernel<<<dim3(16, 16, 4), 256, 0, stream>>>(Wk, WkT, 1024, 1024, flags);
  transpose_kernel<<<dim3(16, 16, 4), 256, 0, stream>>>(Wv, WvT, 1024, 1024, flags);
  transpose_kernel<<<dim3(16, 16, 4), 256, 0, stream>>>(Wo, WoT, 1024, 1024, flags);
  transpose_kernel<<<dim3(64, 16, 4), 256, 0, stream>>>(W1, W1T, 1024, 4096, flags);
  transpose_kernel<<<dim3(16, 64, 4), 256, 0, stream>>>(W2, W2T, 4096, 1024, flags);

  addpe_kernel<<<4096, 256, 0, stream>>>(qe, qa, pe, xf, xb, yb, flags);

  for (int l = 0; l < 4; ++l) {
    // K-proj (z=0) + V-proj (z=1): 512 blocks, 2/CU
    gemm256_kernel<<<dim3(8, 32, 2), 256, 0, stream>>>(
        xb, WkT + (long)l * 1048576, bkc + l * 1024, kb, 0,
        yb, WvT + (long)l * 1048576, bvc + l * 1024, vbf, 0,
        1024, 1024, 1024, 0);
    vtrans_kernel<<<dim3(8, 256), 256, 0, stream>>>(vbf, vtb);
    attn_kernel<<<dim3(256, 2), 256, 0, stream>>>(kb, vtb, frc, vbf);  // ao aliases vbf
    // Wo: split-K=2 (xb is dead here) -> 512 blocks
    gemm256_kernel<<<dim3(8, 32, 2), 256, 0, stream>>>(
        vbf, WoT + (long)l * 1048576, boc + l * 1024, tmpD, 0,
        vbf, WoT + (long)l * 1048576, nullptr,        xb,   512,
        1024, 1024, 512, 0);
    ln_kernel<<<8192, 256, 0, stream>>>(xf, tmpD, xb, g1c + l * 1024, be1c + l * 1024,
                                        xb, nullptr, flags, 0);
    // FF1: 1024 blocks
    gemm256_kernel<<<dim3(32, 32, 1), 256, 0, stream>>>(
        xb, W1T + (long)l * 4194304, b1c + l * 4096, ff1, 0,
        xb, W1T + (long)l * 4194304, b1c + l * 4096, ff1, 0,
        4096, 1024, 1024, 1);
    // FF2: split-K=2 (xb dead after FF1) -> 512 blocks
    gemm256_kernel<<<dim3(8, 32, 2), 256, 0, stream>>>(
        ff1, W2T + (long)l * 4194304, b2c + l * 1024, tmpD, 0,
        ff1, W2T + (long)l * 4194304, nullptr,        xb,   2048,
        1024, 4096, 2048, 0);
    if (l == 3) {
      ln_kernel<<<8192, 256, 0, stream>>>(xf, tmpD, xb, g2c + l * 1024, be2c + l * 1024,
                                          (ushort_t*)d_out, (float*)d_out, flags, 1);
    } else {
      ln_kernel<<<8192, 256, 0, stream>>>(xf, tmpD, xb, g2c + l * 1024, be2c + l * 1024,
                                          xb, nullptr, flags, 0);
    }
  }
}

// Round 13
// 1598.178 us; speedup vs baseline: 1.4061x; 1.0160x over previous
//
#include <hip/hip_runtime.h>
#include <hip/hip_bf16.h>
#include <cstdint>
#include <cstddef>

// Problem constants
#define Bq 16
#define Sq 512
#define Dq 1024
#define Hq 16
#define Lq 4
#define FFq 4096
#define Mq (Bq * Sq)  // 8192

typedef unsigned short ushort_t;
typedef __attribute__((ext_vector_type(8))) short short8;
typedef __attribute__((ext_vector_type(8))) unsigned short ushortx8;
typedef __attribute__((ext_vector_type(4))) unsigned short ushortx4;
typedef __attribute__((ext_vector_type(4))) float floatx4;
typedef __attribute__((ext_vector_type(16))) float floatx16;

__device__ __forceinline__ float bf2f(ushort_t u) {
  union { unsigned int i; float f; } x;
  x.i = ((unsigned int)u) << 16;
  return x.f;
}
__device__ __forceinline__ ushort_t f2bf(float f) {
  unsigned int u = __float_as_uint(f);
  u += 0x7fffu + ((u >> 16) & 1u);
  return (ushort_t)(u >> 16);
}

// async global->LDS, 16B per lane; LDS dest is wave-uniform base + lane*16
#define GLL16(gp, lp) __builtin_amdgcn_global_load_lds( \
    (__attribute__((address_space(1))) void*)(gp),      \
    (__attribute__((address_space(3))) void*)(lp), 16, 0, 0)

template<int N> __device__ __forceinline__ void waitvm() {
  if constexpr (N == 0)       asm volatile("s_waitcnt vmcnt(0)" ::: "memory");
  else if constexpr (N == 6)  asm volatile("s_waitcnt vmcnt(6)" ::: "memory");
  else                        asm volatile("s_waitcnt vmcnt(12)" ::: "memory");
}

// ---------------------------------------------------------------------------
// dtype probe: pe[1] (= cos(0) = 1.0) and ln1_g[0] (= 1.0).
// ---------------------------------------------------------------------------
__global__ void probe_kernel(const ushort_t* __restrict__ pe,
                             const ushort_t* __restrict__ g1,
                             int* __restrict__ flags)
{
  if (threadIdx.x == 0 && blockIdx.x == 0) {
    flags[0] = (pe[1] == (ushort_t)0x3F80u) ? 1 : 0;
    flags[1] = (g1[0] == (ushort_t)0x3F80u) ? 1 : 0;
  }
}

// fused small-tensor canonicalize: 10 segments in one dispatch
struct CvtArgs {
  const void* src[10];
  ushort_t*   dst[10];
  int         n[10];
  int         fi[10];
  int         cum[11];
};
__global__ __launch_bounds__(256) void convert_all_kernel(
    CvtArgs a, const int* __restrict__ flags)
{
  const int bidx = blockIdx.x;
  int s = 0;
  while (s < 9 && bidx >= a.cum[s + 1]) ++s;
  const int i = (bidx - a.cum[s]) * 256 + threadIdx.x;
  if (i >= a.n[s]) return;
  if (flags[a.fi[s]]) a.dst[s][i] = ((const ushort_t*)a.src[s])[i];
  else                a.dst[s][i] = f2bf(((const float*)a.src[s])[i]);
}

// ---------------------------------------------------------------------------
// 256x128 / 32x32x16-MFMA GEMM (r12 config, FROZEN — best measured ~690 TF;
// 9 structural variants all plateaued here). Wave = 128x64 (FR=4, FC=2),
// split-K capable, 3-buffer counted-vmcnt pipeline, T1 slab swizzle, T2
// source-side granule swizzle. C/D layout (m74/m101): col=lane&31,
// row=(reg&3)+8*(reg>>2)+4*(lane>>5). blockIdx.z picks pointer set.
// ---------------------------------------------------------------------------
__global__ __launch_bounds__(256, 2) void gemm256_kernel(
    const ushort_t* __restrict__ A0, const ushort_t* __restrict__ BT0,
    const ushort_t* __restrict__ bias0, ushort_t* __restrict__ C0, int koff0,
    const ushort_t* __restrict__ A1, const ushort_t* __restrict__ BT1,
    const ushort_t* __restrict__ bias1, ushort_t* __restrict__ C1, int koff1,
    int N, int Kst, int Klen, int relu)
{
  __shared__ __align__(16) ushort_t As[3][256 * 32];  // 48 KB
  __shared__ __align__(16) ushort_t Bs[3][128 * 32];  // 24 KB

  const ushort_t* A    = blockIdx.z ? A1 : A0;
  const ushort_t* BT   = blockIdx.z ? BT1 : BT0;
  const ushort_t* bias = blockIdx.z ? bias1 : bias0;
  ushort_t*       C    = blockIdx.z ? C1 : C0;
  const int       koff = blockIdx.z ? koff1 : koff0;

  const int t = threadIdx.x;
  const int l = t & 63;
  const int wid = t >> 6;
  const int l31 = l & 31;
  const int wr = wid >> 1;   // wave M-half (rows 128 each)
  const int wc = wid & 1;    // wave N-half (cols 64 each)

  // ---- T1 XCD slab swizzle (bijective; gy = 32, multiple of 8) ----
  int bx = blockIdx.x, by = blockIdx.y;
  {
    const int gx = gridDim.x, gy = gridDim.y;
    if ((gy & 7) == 0) {
      const int orig = by * gx + bx;
      const int xcd = orig & 7;
      const int local = orig >> 3;
      const int rows = gy >> 3;
      by = xcd * rows + local % rows;
      bx = local / rows;
    }
  }
  const long m0 = (long)by * 256;
  const long n0 = (long)bx * 128;
  const int nk = Klen >> 5;

  // staging (r10-proven): thread t covers row t>>2, granule t&3 per 64-row
  // chunk; T2 inverse swizzle on SOURCE column; LDS stays linear.
  const int srow = t >> 2;
  const int scol = (((t & 3) ^ ((srow >> 1) & 3)) << 3);
  const ushort_t* sA = A + (m0 + srow) * (long)Kst + koff + scol;
  const ushort_t* sB = BT + (n0 + srow) * (long)Kst + koff + scol;
  const long rs64 = 64L * (long)Kst;
  const int lws = wid * 512;   // wave-uniform LDS elem base within a chunk

#define STG(buf_, kt_) do {                                            \
    const long ko_ = (long)(kt_) << 5;                                 \
    GLL16(sA + ko_,            &As[(buf_)][lws]);                      \
    GLL16(sA + rs64 + ko_,     &As[(buf_)][2048 + lws]);               \
    GLL16(sA + 2 * rs64 + ko_, &As[(buf_)][4096 + lws]);               \
    GLL16(sA + 3 * rs64 + ko_, &As[(buf_)][6144 + lws]);               \
    GLL16(sB + ko_,            &Bs[(buf_)][lws]);                      \
    GLL16(sB + rs64 + ko_,     &Bs[(buf_)][2048 + lws]);               \
  } while (0)

  floatx16 acc[4][2];
#pragma unroll
  for (int i = 0; i < 4; ++i)
#pragma unroll
    for (int j = 0; j < 2; ++j)
#pragma unroll
      for (int r = 0; r < 16; ++r) acc[i][j][r] = 0.0f;

  // frag-read swizzled column offsets (r9-verified): granule = sl*2+(l>>5),
  // XOR'd with row bits ((l>>1)&3 == (row>>1)&3 for all frag rows).
  const int xo = (l >> 1) & 3;
  const int co0 = (((l >> 5)) ^ xo) << 3;       // k-slice 0
  const int co1 = ((2 + (l >> 5)) ^ xo) << 3;   // k-slice 1
  const int arow = wr * 128 + l31;              // + fr*32
  const int brow = wc * 64 + l31;               // + fc*32

  // prologue: 2 tiles staged ahead
  STG(0, 0);
  if (nk > 1) STG(1, 1);

  for (int kt = 0; kt < nk; ++kt) {
    const int buf = kt % 3;
    if (kt + 2 < nk) { STG((kt + 2) % 3, kt + 2); waitvm<12>(); }
    else if (kt + 1 < nk) waitvm<6>();
    else waitvm<0>();
    __builtin_amdgcn_s_barrier();
    __builtin_amdgcn_sched_barrier(0);

    short8 a[4][2], b[2][2];
#pragma unroll
    for (int fr = 0; fr < 4; ++fr) {
      a[fr][0] = *(const short8*)&As[buf][(arow + fr * 32) * 32 + co0];
      a[fr][1] = *(const short8*)&As[buf][(arow + fr * 32) * 32 + co1];
    }
#pragma unroll
    for (int fc = 0; fc < 2; ++fc) {
      b[fc][0] = *(const short8*)&Bs[buf][(brow + fc * 32) * 32 + co0];
      b[fc][1] = *(const short8*)&Bs[buf][(brow + fc * 32) * 32 + co1];
    }

#pragma unroll
    for (int sl = 0; sl < 2; ++sl)
#pragma unroll
      for (int fc = 0; fc < 2; ++fc)
#pragma unroll
        for (int fr = 0; fr < 4; ++fr)
          acc[fr][fc] = __builtin_amdgcn_mfma_f32_32x32x16_bf16(
              a[fr][sl], b[fc][sl], acc[fr][fc], 0, 0, 0);

    __builtin_amdgcn_s_barrier();
  }
#undef STG

  // epilogue: C/D col=lane&31, row=(reg&3)+8*(reg>>2)+4*(lane>>5)
#pragma unroll
  for (int fc = 0; fc < 2; ++fc) {
    const long col = n0 + wc * 64 + fc * 32 + l31;
    const float bsv = bias ? bf2f(bias[col]) : 0.0f;
#pragma unroll
    for (int fr = 0; fr < 4; ++fr) {
      const floatx16 v = acc[fr][fc];
      const long rbase = m0 + wr * 128 + fr * 32 + 4 * (l >> 5);
#pragma unroll
      for (int r = 0; r < 16; ++r) {
        const long row = rbase + (r & 3) + 8 * (r >> 2);
        float x = v[r] + bsv;
        if (relu) x = fmaxf(x, 0.0f);
        C[row * N + col] = f2bf(x);
      }
    }
  }
}

// ---------------------------------------------------------------------------
// Fused causal attention. kq: [B,S,D] (k==q), vt: [B,H,64,S] (V^T per head),
// fr: bf16 [B*S]. scores = (q.k)*0.125*fr[i], mask j>=i, row 0 zeroed.
// Load balance (r13): wq = 2*w4 + blockIdx.y interleaves row-bands so the
// two blocks of a head do 16 vs 20 j-tiles (was 10 vs 26).
// ---------------------------------------------------------------------------
__global__ __launch_bounds__(256) void attn_kernel(
    const ushort_t* __restrict__ kq, const ushort_t* __restrict__ vt,
    const ushort_t* __restrict__ fr, ushort_t* __restrict__ ao)
{
  __shared__ __align__(16) ushort_t P[4][64 * 72];
  const int t = threadIdx.x;
  const int lane = t & 63;
  const int w4 = t >> 6;
  const int wq = w4 * 2 + blockIdx.y;   // balanced band interleave
  const int b = blockIdx.x >> 4;
  const int h = blockIdx.x & 15;
  const int la = lane & 15;
  const int lb = lane >> 4;
  const int i0 = wq * 64;
  const long kbase = ((long)b * Sq) * Dq + h * 64;
  const long vbase = ((long)(b * Hq + h)) * (64L * Sq);

  short8 qf[4][2];
#pragma unroll
  for (int mf = 0; mf < 4; ++mf)
#pragma unroll
    for (int tt = 0; tt < 2; ++tt)
      qf[mf][tt] = *(const short8*)&kq[kbase + (long)(i0 + mf * 16 + la) * Dq + tt * 32 + lb * 8];

  float frs[4][4];
#pragma unroll
  for (int mf = 0; mf < 4; ++mf)
#pragma unroll
    for (int r = 0; r < 4; ++r)
      frs[mf][r] = 0.125f * bf2f(fr[b * Sq + i0 + mf * 16 + lb * 4 + r]);

  const floatx4 z4 = {0.f, 0.f, 0.f, 0.f};
  floatx4 o[4][4];
  float mrun[4][4], lrun[4][4];
#pragma unroll
  for (int mf = 0; mf < 4; ++mf)
#pragma unroll
    for (int x = 0; x < 4; ++x) {
      o[mf][x] = z4;
      mrun[mf][x] = -1e30f;
      lrun[mf][x] = 0.0f;
    }

  for (int jt = 0; jt <= wq; ++jt) {
    const int j0 = jt * 64;
    floatx4 s[4][4];
#pragma unroll
    for (int mf = 0; mf < 4; ++mf)
#pragma unroll
      for (int jf = 0; jf < 4; ++jf) s[mf][jf] = z4;

#pragma unroll
    for (int tt = 0; tt < 2; ++tt) {
      short8 kf[4];
#pragma unroll
      for (int jf = 0; jf < 4; ++jf)
        kf[jf] = *(const short8*)&kq[kbase + (long)(j0 + jf * 16 + la) * Dq + tt * 32 + lb * 8];
#pragma unroll
      for (int mf = 0; mf < 4; ++mf)
#pragma unroll
        for (int jf = 0; jf < 4; ++jf)
          s[mf][jf] = __builtin_amdgcn_mfma_f32_16x16x32_bf16(qf[mf][tt], kf[jf], s[mf][jf], 0, 0, 0);
    }

    const bool diag = (jt == wq);
#pragma unroll
    for (int mf = 0; mf < 4; ++mf)
#pragma unroll
      for (int jf = 0; jf < 4; ++jf)
#pragma unroll
        for (int r = 0; r < 4; ++r) {
          float x = s[mf][jf][r] * frs[mf][r];
          if (diag && (j0 + jf * 16 + la) >= (i0 + mf * 16 + lb * 4 + r)) x = -1e30f;
          s[mf][jf][r] = x;
        }

#pragma unroll
    for (int mf = 0; mf < 4; ++mf)
#pragma unroll
      for (int r = 0; r < 4; ++r) {
        float pm = fmaxf(fmaxf(s[mf][0][r], s[mf][1][r]), fmaxf(s[mf][2][r], s[mf][3][r]));
        pm = fmaxf(pm, __shfl_xor(pm, 1));
        pm = fmaxf(pm, __shfl_xor(pm, 2));
        pm = fmaxf(pm, __shfl_xor(pm, 4));
        pm = fmaxf(pm, __shfl_xor(pm, 8));
        const float mo = mrun[mf][r];
        const float mn = fmaxf(mo, pm);
        const float sc = __expf(mo - mn);
        mrun[mf][r] = mn;
        float rs = 0.0f;
#pragma unroll
        for (int jf = 0; jf < 4; ++jf) {
          const float p = __expf(s[mf][jf][r] - mn);
          s[mf][jf][r] = p;
          rs += p;
        }
        rs += __shfl_xor(rs, 1);
        rs += __shfl_xor(rs, 2);
        rs += __shfl_xor(rs, 4);
        rs += __shfl_xor(rs, 8);
        lrun[mf][r] = lrun[mf][r] * sc + rs;
#pragma unroll
        for (int df = 0; df < 4; ++df) o[mf][df][r] *= sc;
      }

    // P tile is wave-private LDS; same-wave ds_write->ds_read, no barrier
#pragma unroll
    for (int mf = 0; mf < 4; ++mf)
#pragma unroll
      for (int jf = 0; jf < 4; ++jf)
#pragma unroll
        for (int r = 0; r < 4; ++r)
          P[w4][(mf * 16 + lb * 4 + r) * 72 + jf * 16 + la] = f2bf(s[mf][jf][r]);

#pragma unroll
    for (int tt = 0; tt < 2; ++tt) {
      short8 pf[4], vf[4];
#pragma unroll
      for (int mf = 0; mf < 4; ++mf)
        pf[mf] = *(const short8*)&P[w4][(mf * 16 + la) * 72 + tt * 32 + lb * 8];
#pragma unroll
      for (int df = 0; df < 4; ++df)
        vf[df] = *(const short8*)&vt[vbase + (long)(df * 16 + la) * Sq + j0 + tt * 32 + lb * 8];
#pragma unroll
      for (int mf = 0; mf < 4; ++mf)
#pragma unroll
        for (int df = 0; df < 4; ++df)
          o[mf][df] = __builtin_amdgcn_mfma_f32_16x16x32_bf16(pf[mf], vf[df], o[mf][df], 0, 0, 0);
    }
  }

#pragma unroll
  for (int mf = 0; mf < 4; ++mf)
#pragma unroll
    for (int df = 0; df < 4; ++df)
#pragma unroll
      for (int r = 0; r < 4; ++r) {
        const int ii = i0 + mf * 16 + lb * 4 + r;
        const float vv = (ii == 0) ? 0.0f : o[mf][df][r] / lrun[mf][r];
        ao[((long)b * Sq + ii) * Dq + h * 64 + df * 16 + la] = f2bf(vv);
      }
}

// ---------------------------------------------------------------------------
// Fused residual-add + LayerNorm, bf16 residual stream (r13):
// v = prev + add (+ add2); y = LN(v)*g + b -> out (bf16, serves as both
// residual carrier and next-GEMM input). final_==1: d_out per flags[0].
// ---------------------------------------------------------------------------
__global__ __launch_bounds__(256) void ln_kernel(
    const ushort_t* __restrict__ prev, const ushort_t* __restrict__ add,
    const ushort_t* __restrict__ add2,
    const ushort_t* __restrict__ g, const ushort_t* __restrict__ bb,
    ushort_t* __restrict__ outb, float* __restrict__ outf,
    const int* __restrict__ flags, int final_)
{
  __shared__ float red[2][4];
  const long row = blockIdx.x;
  const int t = threadIdx.x;
  const int c = t * 4;

  ushortx4 pv = *(const ushortx4*)&prev[row * Dq + c];
  ushortx4 av = *(const ushortx4*)&add[row * Dq + c];
  ushortx4 a2v;
  if (add2) a2v = *(const ushortx4*)&add2[row * Dq + c];
  float v[4];
  float s1 = 0.f, s2 = 0.f;
#pragma unroll
  for (int e = 0; e < 4; ++e) {
    float av_ = bf2f(av[e]);
    if (add2) av_ += bf2f(a2v[e]);
    v[e] = bf2f(pv[e]) + av_;
    s1 += v[e];
    s2 += v[e] * v[e];
  }
#pragma unroll
  for (int m = 1; m < 64; m <<= 1) {
    s1 += __shfl_xor(s1, m);
    s2 += __shfl_xor(s2, m);
  }
  const int lane = t & 63, w = t >> 6;
  if (lane == 0) { red[0][w] = s1; red[1][w] = s2; }
  __syncthreads();
  s1 = red[0][0] + red[0][1] + red[0][2] + red[0][3];
  s2 = red[1][0] + red[1][1] + red[1][2] + red[1][3];
  const float mean = s1 * (1.0f / Dq);
  const float var = fmaxf(s2 * (1.0f / Dq) - mean * mean, 0.0f);
  const float rstd = rsqrtf(var + 1e-5f);
  ushortx4 gv = *(const ushortx4*)&g[c];
  ushortx4 bv = *(const ushortx4*)&bb[c];
  ushortx4 ob;
  floatx4 xo;
#pragma unroll
  for (int e = 0; e < 4; ++e) {
    const float y = (v[e] - mean) * rstd * bf2f(gv[e]) + bf2f(bv[e]);
    xo[e] = y;
    ob[e] = f2bf(y);
  }
  if (final_ && !flags[0]) {
    *(floatx4*)&outf[row * Dq + c] = xo;
  } else {
    *(ushortx4*)&outb[row * Dq + c] = ob;
  }
}

// x = qe + pe (bf16), y = qa + pe (bf16); flag-aware source dtype
__global__ __launch_bounds__(256) void addpe_kernel(
    const void* __restrict__ qe, const void* __restrict__ qa,
    const void* __restrict__ pe,
    ushort_t* __restrict__ xb, ushort_t* __restrict__ yb,
    const int* __restrict__ flags)
{
  const long i = ((long)blockIdx.x * 256 + threadIdx.x) * 8;
  const long sd = i & ((long)Sq * Dq - 1);
  const bool isb = flags[0] != 0;
  float q[8], a[8], p[8];
  if (isb) {
    ushortx8 q8 = *(const ushortx8*)((const ushort_t*)qe + i);
    ushortx8 a8 = *(const ushortx8*)((const ushort_t*)qa + i);
    ushortx8 p8 = *(const ushortx8*)((const ushort_t*)pe + sd);
#pragma unroll
    for (int e = 0; e < 8; ++e) { q[e] = bf2f(q8[e]); a[e] = bf2f(a8[e]); p[e] = bf2f(p8[e]); }
  } else {
    const float* qp = (const float*)qe + i;
    const float* ap = (const float*)qa + i;
    const float* pp = (const float*)pe + sd;
    floatx4 q0 = *(const floatx4*)qp, q1 = *(const floatx4*)(qp + 4);
    floatx4 a0 = *(const floatx4*)ap, a1 = *(const floatx4*)(ap + 4);
    floatx4 p0 = *(const floatx4*)pp, p1 = *(const floatx4*)(pp + 4);
#pragma unroll
    for (int e = 0; e < 4; ++e) {
      q[e] = q0[e]; q[e + 4] = q1[e];
      a[e] = a0[e]; a[e + 4] = a1[e];
      p[e] = p0[e]; p[e + 4] = p1[e];
    }
  }
  ushortx8 xo, yo;
#pragma unroll
  for (int e = 0; e < 8; ++e) {
    const float xvv = (isb ? q[e] : bf2f(f2bf(q[e]))) + (isb ? p[e] : bf2f(f2bf(p[e])));
    const float yvv = (isb ? a[e] : bf2f(f2bf(a[e]))) + (isb ? p[e] : bf2f(f2bf(p[e])));
    xo[e] = f2bf(xvv);
    yo[e] = f2bf(yvv);
  }
  *(ushortx8*)&xb[i] = xo;
  *(ushortx8*)&yb[i] = yo;
}

// dst[z][n][k] = src[z][k][n]; flag-aware source dtype (weights: flags[1])
__global__ __launch_bounds__(256) void transpose_kernel(
    const void* __restrict__ src, ushort_t* __restrict__ dst, int K, int N,
    const int* __restrict__ flags)
{
  __shared__ __align__(16) ushort_t tile[64][72];
  const bool isb = flags[1] != 0;
  const long base = (long)blockIdx.z * K * N;
  const int k0 = blockIdx.y * 64, n0 = blockIdx.x * 64;
  const int t = threadIdx.x;
  const int r = t >> 3;
  const int cc = (t & 7) << 3;
#pragma unroll
  for (int it = 0; it < 2; ++it) {
    const int rr = r + it * 32;
    const long gi = base + (long)(k0 + rr) * N + n0 + cc;
    if (isb) {
      *(short8*)&tile[rr][cc] = *(const short8*)((const ushort_t*)src + gi);
    } else {
      const float* sf = (const float*)src + gi;
      floatx4 v0 = *(const floatx4*)sf;
      floatx4 v1 = *(const floatx4*)(sf + 4);
#pragma unroll
      for (int e = 0; e < 4; ++e) {
        tile[rr][cc + e] = f2bf(v0[e]);
        tile[rr][cc + 4 + e] = f2bf(v1[e]);
      }
    }
  }
  __syncthreads();
#pragma unroll
  for (int it = 0; it < 2; ++it) {
    const int rr = r + it * 32;
    short8 v;
#pragma unroll
    for (int e = 0; e < 8; ++e) v[e] = (short)tile[cc + e][rr];
    *(short8*)&dst[base + (long)(n0 + rr) * K + k0 + cc] = v;
  }
}

// vt[b][h][d][j] = vb[b][j][h*64+d]  (vb is bf16 workspace, no flag needed)
__global__ __launch_bounds__(256) void vtrans_kernel(
    const ushort_t* __restrict__ vb, ushort_t* __restrict__ vt)
{
  __shared__ __align__(16) ushort_t tile[64][72];
  const int b = blockIdx.y >> 4, h = blockIdx.y & 15;
  const int j0 = blockIdx.x * 64;
  const int t = threadIdx.x;
  const int r = t >> 3;
  const int cc = (t & 7) << 3;
#pragma unroll
  for (int it = 0; it < 2; ++it) {
    const int rr = r + it * 32;
    *(short8*)&tile[rr][cc] = *(const short8*)&vb[((long)b * Sq + j0 + rr) * Dq + h * 64 + cc];
  }
  __syncthreads();
#pragma unroll
  for (int it = 0; it < 2; ++it) {
    const int rr = r + it * 32;
    short8 v;
#pragma unroll
    for (int e = 0; e < 8; ++e) v[e] = (short)tile[cc + e][rr];
    *(short8*)&vt[((long)(b * Hq + h) * 64 + rr) * Sq + j0 + cc] = v;
  }
}

extern "C" void kernel_launch(void* const* d_in, const int* in_sizes, int n_in,
                              void* d_out, int out_size, void* d_ws, size_t ws_size,
                              hipStream_t stream)
{
  if (n_in < 18) return;
  const void* qe  = d_in[0];
  const void* qa  = d_in[1];
  const void* fr  = d_in[2];
  const void* pe  = d_in[3];
  const void* Wk  = d_in[4];
  const void* bk  = d_in[5];
  const void* Wv  = d_in[6];
  const void* bv  = d_in[7];
  const void* Wo  = d_in[8];
  const void* bo  = d_in[9];
  const void* W1  = d_in[10];
  const void* b1  = d_in[11];
  const void* W2  = d_in[12];
  const void* b2  = d_in[13];
  const void* g1  = d_in[14];
  const void* be1 = d_in[15];
  const void* g2  = d_in[16];
  const void* be2 = d_in[17];

  char* ws = (char*)d_ws;
  const size_t SM = 243269632L;
  const size_t NEED = SM + 114752L;
  if (ws_size < NEED) return;

  ushort_t* xb   = (ushort_t*)(ws + 33554432L);   // bf16 residual / GEMM input
  ushort_t* yb   = (ushort_t*)(ws + 50331648L);
  ushort_t* tmpD = (ushort_t*)(ws + 67108864L);
  ushort_t* WkT  = (ushort_t*)(ws + 83886080L);
  ushort_t* WvT  = (ushort_t*)(ws + 92274688L);
  ushort_t* WoT  = (ushort_t*)(ws + 100663296L);
  ushort_t* W1T  = (ushort_t*)(ws + 109051904L);
  ushort_t* W2T  = (ushort_t*)(ws + 142606336L);
  ushort_t* kb   = (ushort_t*)(ws + 176160768L);
  ushort_t* vbf  = (ushort_t*)(ws + 192937984L);
  ushort_t* vtb  = (ushort_t*)(ws + 209715200L);  // V^T; split-K partial slab after attn
  ushort_t* ff1  = kb;  // 64 MiB region, disjoint lifetime

  int*      flags = (int*)(ws + SM);
  ushort_t* frc  = (ushort_t*)(ws + SM + 64);
  ushort_t* bkc  = (ushort_t*)(ws + SM + 16448);
  ushort_t* bvc  = (ushort_t*)(ws + SM + 24640);
  ushort_t* boc  = (ushort_t*)(ws + SM + 32832);
  ushort_t* b1c  = (ushort_t*)(ws + SM + 41024);
  ushort_t* b2c  = (ushort_t*)(ws + SM + 73792);
  ushort_t* g1c  = (ushort_t*)(ws + SM + 81984);
  ushort_t* be1c = (ushort_t*)(ws + SM + 90176);
  ushort_t* g2c  = (ushort_t*)(ws + SM + 98368);
  ushort_t* be2c = (ushort_t*)(ws + SM + 106560);

  probe_kernel<<<1, 64, 0, stream>>>((const ushort_t*)pe, (const ushort_t*)g1, flags);

  {
    CvtArgs a;
    const void* srcs[10] = {fr, bk, bv, bo, b1, b2, g1, be1, g2, be2};
    ushort_t*   dsts[10] = {frc, bkc, bvc, boc, b1c, b2c, g1c, be1c, g2c, be2c};
    const int   ns[10]   = {8192, 4096, 4096, 4096, 16384, 4096, 4096, 4096, 4096, 4096};
    int cum = 0;
    for (int s = 0; s < 10; ++s) {
      a.src[s] = srcs[s]; a.dst[s] = dsts[s]; a.n[s] = ns[s];
      a.fi[s] = (s == 0) ? 0 : 1;
      a.cum[s] = cum;
      cum += (ns[s] + 255) / 256;
    }
    a.cum[10] = cum;
    convert_all_kernel<<<cum, 256, 0, stream>>>(a, flags);
  }

  transpose_kernel<<<dim3(16, 16, 4), 256, 0, stream>>>(Wk, WkT, 1024, 1024, flags);
  transpose_kernel<<<dim3(16, 16, 4), 256, 0, stream>>>(Wv, WvT, 1024, 1024, flags);
  transpose_kernel<<<dim3(16, 16, 4), 256, 0, stream>>>(Wo, WoT, 1024, 1024, flags);
  transpose_kernel<<<dim3(64, 16, 4), 256, 0, stream>>>(W1, W1T, 1024, 4096, flags);
  transpose_kernel<<<dim3(16, 64, 4), 256, 0, stream>>>(W2, W2T, 4096, 1024, flags);

  addpe_kernel<<<4096, 256, 0, stream>>>(qe, qa, pe, xb, yb, flags);

  for (int l = 0; l < 4; ++l) {
    // K-proj (z=0) + V-proj (z=1): 512 blocks
    gemm256_kernel<<<dim3(8, 32, 2), 256, 0, stream>>>(
        xb, WkT + (long)l * 1048576, bkc + l * 1024, kb, 0,
        yb, WvT + (long)l * 1048576, bvc + l * 1024, vbf, 0,
        1024, 1024, 1024, 0);
    vtrans_kernel<<<dim3(8, 256), 256, 0, stream>>>(vbf, vtb);
    attn_kernel<<<dim3(256, 2), 256, 0, stream>>>(kb, vtb, frc, vbf);  // ao aliases vbf
    // Wo: split-K=2, partial to vtb (dead after attn) -> 512 blocks
    gemm256_kernel<<<dim3(8, 32, 2), 256, 0, stream>>>(
        vbf, WoT + (long)l * 1048576, boc + l * 1024, tmpD, 0,
        vbf, WoT + (long)l * 1048576, nullptr,        vtb,  512,
        1024, 1024, 512, 0);
    ln_kernel<<<8192, 256, 0, stream>>>(xb, tmpD, vtb, g1c + l * 1024, be1c + l * 1024,
                                        xb, nullptr, flags, 0);
    // FF1: 1024 blocks
    gemm256_kernel<<<dim3(32, 32, 1), 256, 0, stream>>>(
        xb, W1T + (long)l * 4194304, b1c + l * 4096, ff1, 0,
        xb, W1T + (long)l * 4194304, b1c + l * 4096, ff1, 0,
        4096, 1024, 1024, 1);
    // FF2: split-K=2, partial to vtb -> 512 blocks
    gemm256_kernel<<<dim3(8, 32, 2), 256, 0, stream>>>(
        ff1, W2T + (long)l * 4194304, b2c + l * 1024, tmpD, 0,
        ff1, W2T + (long)l * 4194304, nullptr,        vtb,  2048,
        1024, 4096, 2048, 0);
    if (l == 3) {
      ln_kernel<<<8192, 256, 0, stream>>>(xb, tmpD, vtb, g2c + l * 1024, be2c + l * 1024,
                                          (ushort_t*)d_out, (float*)d_out, flags, 1);
    } else {
      ln_kernel<<<8192, 256, 0, stream>>>(xb, tmpD, vtb, g2c + l * 1024, be2c + l * 1024,
                                          xb, nullptr, flags, 0);
    }
  }
}

// Round 14
// 1529.955 us; speedup vs baseline: 1.4688x; 1.0446x over previous
//
#include <hip/hip_runtime.h>
#include <hip/hip_bf16.h>
#include <cstdint>
#include <cstddef>

// Problem constants
#define Bq 16
#define Sq 512
#define Dq 1024
#define Hq 16
#define Lq 4
#define FFq 4096
#define Mq (Bq * Sq)  // 8192

typedef unsigned short ushort_t;
typedef __attribute__((ext_vector_type(8))) short short8;
typedef __attribute__((ext_vector_type(8))) unsigned short ushortx8;
typedef __attribute__((ext_vector_type(4))) unsigned short ushortx4;
typedef __attribute__((ext_vector_type(4))) float floatx4;
typedef __attribute__((ext_vector_type(16))) float floatx16;

__device__ __forceinline__ float bf2f(ushort_t u) {
  union { unsigned int i; float f; } x;
  x.i = ((unsigned int)u) << 16;
  return x.f;
}
__device__ __forceinline__ ushort_t f2bf(float f) {
  unsigned int u = __float_as_uint(f);
  u += 0x7fffu + ((u >> 16) & 1u);
  return (ushort_t)(u >> 16);
}

// async global->LDS, 16B per lane; LDS dest is wave-uniform base + lane*16
#define GLL16(gp, lp) __builtin_amdgcn_global_load_lds( \
    (__attribute__((address_space(1))) void*)(gp),      \
    (__attribute__((address_space(3))) void*)(lp), 16, 0, 0)

template<int N> __device__ __forceinline__ void waitvm() {
  if constexpr (N == 0)       asm volatile("s_waitcnt vmcnt(0)" ::: "memory");
  else if constexpr (N == 6)  asm volatile("s_waitcnt vmcnt(6)" ::: "memory");
  else                        asm volatile("s_waitcnt vmcnt(12)" ::: "memory");
}

// ---------------------------------------------------------------------------
// dtype probe: pe[1] (= cos(0) = 1.0) and ln1_g[0] (= 1.0).
// ---------------------------------------------------------------------------
__global__ void probe_kernel(const ushort_t* __restrict__ pe,
                             const ushort_t* __restrict__ g1,
                             int* __restrict__ flags)
{
  if (threadIdx.x == 0 && blockIdx.x == 0) {
    flags[0] = (pe[1] == (ushort_t)0x3F80u) ? 1 : 0;
    flags[1] = (g1[0] == (ushort_t)0x3F80u) ? 1 : 0;
  }
}

// fused small-tensor canonicalize: 10 segments in one dispatch
struct CvtArgs {
  const void* src[10];
  ushort_t*   dst[10];
  int         n[10];
  int         fi[10];
  int         cum[11];
};
__global__ __launch_bounds__(256) void convert_all_kernel(
    CvtArgs a, const int* __restrict__ flags)
{
  const int bidx = blockIdx.x;
  int s = 0;
  while (s < 9 && bidx >= a.cum[s + 1]) ++s;
  const int i = (bidx - a.cum[s]) * 256 + threadIdx.x;
  if (i >= a.n[s]) return;
  if (flags[a.fi[s]]) a.dst[s][i] = ((const ushort_t*)a.src[s])[i];
  else                a.dst[s][i] = f2bf(((const float*)a.src[s])[i]);
}

// ---------------------------------------------------------------------------
// 256x128 / 32x32x16-MFMA GEMM (r12 config, FROZEN — best measured ~690 TF).
// Wave = 128x64 (FR=4, FC=2), split-K capable, 3-buffer counted-vmcnt
// pipeline, T1 slab swizzle, T2 source-side granule swizzle. C/D layout
// (m74/m101): col=lane&31, row=(reg&3)+8*(reg>>2)+4*(lane>>5).
// ---------------------------------------------------------------------------
__global__ __launch_bounds__(256, 2) void gemm256_kernel(
    const ushort_t* __restrict__ A0, const ushort_t* __restrict__ BT0,
    const ushort_t* __restrict__ bias0, ushort_t* __restrict__ C0, int koff0,
    const ushort_t* __restrict__ A1, const ushort_t* __restrict__ BT1,
    const ushort_t* __restrict__ bias1, ushort_t* __restrict__ C1, int koff1,
    int N, int Kst, int Klen, int relu)
{
  __shared__ __align__(16) ushort_t As[3][256 * 32];  // 48 KB
  __shared__ __align__(16) ushort_t Bs[3][128 * 32];  // 24 KB

  const ushort_t* A    = blockIdx.z ? A1 : A0;
  const ushort_t* BT   = blockIdx.z ? BT1 : BT0;
  const ushort_t* bias = blockIdx.z ? bias1 : bias0;
  ushort_t*       C    = blockIdx.z ? C1 : C0;
  const int       koff = blockIdx.z ? koff1 : koff0;

  const int t = threadIdx.x;
  const int l = t & 63;
  const int wid = t >> 6;
  const int l31 = l & 31;
  const int wr = wid >> 1;
  const int wc = wid & 1;

  // ---- T1 XCD slab swizzle (bijective; gy = 32, multiple of 8) ----
  int bx = blockIdx.x, by = blockIdx.y;
  {
    const int gx = gridDim.x, gy = gridDim.y;
    if ((gy & 7) == 0) {
      const int orig = by * gx + bx;
      const int xcd = orig & 7;
      const int local = orig >> 3;
      const int rows = gy >> 3;
      by = xcd * rows + local % rows;
      bx = local / rows;
    }
  }
  const long m0 = (long)by * 256;
  const long n0 = (long)bx * 128;
  const int nk = Klen >> 5;

  const int srow = t >> 2;
  const int scol = (((t & 3) ^ ((srow >> 1) & 3)) << 3);
  const ushort_t* sA = A + (m0 + srow) * (long)Kst + koff + scol;
  const ushort_t* sB = BT + (n0 + srow) * (long)Kst + koff + scol;
  const long rs64 = 64L * (long)Kst;
  const int lws = wid * 512;

#define STG(buf_, kt_) do {                                            \
    const long ko_ = (long)(kt_) << 5;                                 \
    GLL16(sA + ko_,            &As[(buf_)][lws]);                      \
    GLL16(sA + rs64 + ko_,     &As[(buf_)][2048 + lws]);               \
    GLL16(sA + 2 * rs64 + ko_, &As[(buf_)][4096 + lws]);               \
    GLL16(sA + 3 * rs64 + ko_, &As[(buf_)][6144 + lws]);               \
    GLL16(sB + ko_,            &Bs[(buf_)][lws]);                      \
    GLL16(sB + rs64 + ko_,     &Bs[(buf_)][2048 + lws]);               \
  } while (0)

  floatx16 acc[4][2];
#pragma unroll
  for (int i = 0; i < 4; ++i)
#pragma unroll
    for (int j = 0; j < 2; ++j)
#pragma unroll
      for (int r = 0; r < 16; ++r) acc[i][j][r] = 0.0f;

  const int xo = (l >> 1) & 3;
  const int co0 = (((l >> 5)) ^ xo) << 3;
  const int co1 = ((2 + (l >> 5)) ^ xo) << 3;
  const int arow = wr * 128 + l31;
  const int brow = wc * 64 + l31;

  STG(0, 0);
  if (nk > 1) STG(1, 1);

  for (int kt = 0; kt < nk; ++kt) {
    const int buf = kt % 3;
    if (kt + 2 < nk) { STG((kt + 2) % 3, kt + 2); waitvm<12>(); }
    else if (kt + 1 < nk) waitvm<6>();
    else waitvm<0>();
    __builtin_amdgcn_s_barrier();
    __builtin_amdgcn_sched_barrier(0);

    short8 a[4][2], b[2][2];
#pragma unroll
    for (int fr = 0; fr < 4; ++fr) {
      a[fr][0] = *(const short8*)&As[buf][(arow + fr * 32) * 32 + co0];
      a[fr][1] = *(const short8*)&As[buf][(arow + fr * 32) * 32 + co1];
    }
#pragma unroll
    for (int fc = 0; fc < 2; ++fc) {
      b[fc][0] = *(const short8*)&Bs[buf][(brow + fc * 32) * 32 + co0];
      b[fc][1] = *(const short8*)&Bs[buf][(brow + fc * 32) * 32 + co1];
    }

#pragma unroll
    for (int sl = 0; sl < 2; ++sl)
#pragma unroll
      for (int fc = 0; fc < 2; ++fc)
#pragma unroll
        for (int fr = 0; fr < 4; ++fr)
          acc[fr][fc] = __builtin_amdgcn_mfma_f32_32x32x16_bf16(
              a[fr][sl], b[fc][sl], acc[fr][fc], 0, 0, 0);

    __builtin_amdgcn_s_barrier();
  }
#undef STG

#pragma unroll
  for (int fc = 0; fc < 2; ++fc) {
    const long col = n0 + wc * 64 + fc * 32 + l31;
    const float bsv = bias ? bf2f(bias[col]) : 0.0f;
#pragma unroll
    for (int fr = 0; fr < 4; ++fr) {
      const floatx16 v = acc[fr][fc];
      const long rbase = m0 + wr * 128 + fr * 32 + 4 * (l >> 5);
#pragma unroll
      for (int r = 0; r < 16; ++r) {
        const long row = rbase + (r & 3) + 8 * (r >> 2);
        float x = v[r] + bsv;
        if (relu) x = fmaxf(x, 0.0f);
        C[row * N + col] = f2bf(x);
      }
    }
  }
}

// ---------------------------------------------------------------------------
// Fused causal attention — r14: one wave (64 thr) per 32-row q-band.
// 4096 independent blocks (B*H*16 bands), ~110 VGPR -> 4 waves/SIMD target,
// fine-grained balance (band b needs b/2+1 j-tiles). Math identical to the
// r2-r13-verified kernel, just MF=2.
// kq: [B,S,D] (k==q), vt: [B,H,64,S], fr bf16 [B*S].
// ---------------------------------------------------------------------------
__global__ __launch_bounds__(64, 4) void attn_kernel(
    const ushort_t* __restrict__ kq, const ushort_t* __restrict__ vt,
    const ushort_t* __restrict__ fr, ushort_t* __restrict__ ao)
{
  __shared__ __align__(16) ushort_t P[32 * 72];
  const int lane = threadIdx.x;
  const int band = blockIdx.y;          // 0..15
  const int b = blockIdx.x >> 4;
  const int h = blockIdx.x & 15;
  const int la = lane & 15;
  const int lb = lane >> 4;
  const int i0 = band * 32;
  const int ntiles = (band >> 1) + 1;
  const long kbase = ((long)b * Sq) * Dq + h * 64;
  const long vbase = ((long)(b * Hq + h)) * (64L * Sq);

  short8 qf[2][2];
#pragma unroll
  for (int mf = 0; mf < 2; ++mf)
#pragma unroll
    for (int tt = 0; tt < 2; ++tt)
      qf[mf][tt] = *(const short8*)&kq[kbase + (long)(i0 + mf * 16 + la) * Dq + tt * 32 + lb * 8];

  float frs[2][4];
#pragma unroll
  for (int mf = 0; mf < 2; ++mf)
#pragma unroll
    for (int r = 0; r < 4; ++r)
      frs[mf][r] = 0.125f * bf2f(fr[b * Sq + i0 + mf * 16 + lb * 4 + r]);

  const floatx4 z4 = {0.f, 0.f, 0.f, 0.f};
  floatx4 o[2][4];
  float mrun[2][4], lrun[2][4];
#pragma unroll
  for (int mf = 0; mf < 2; ++mf)
#pragma unroll
    for (int x = 0; x < 4; ++x) {
      o[mf][x] = z4;
      mrun[mf][x] = -1e30f;
      lrun[mf][x] = 0.0f;
    }

  for (int jt = 0; jt < ntiles; ++jt) {
    const int j0 = jt * 64;
    floatx4 s[2][4];
#pragma unroll
    for (int mf = 0; mf < 2; ++mf)
#pragma unroll
      for (int jf = 0; jf < 4; ++jf) s[mf][jf] = z4;

#pragma unroll
    for (int tt = 0; tt < 2; ++tt) {
      short8 kf[4];
#pragma unroll
      for (int jf = 0; jf < 4; ++jf)
        kf[jf] = *(const short8*)&kq[kbase + (long)(j0 + jf * 16 + la) * Dq + tt * 32 + lb * 8];
#pragma unroll
      for (int mf = 0; mf < 2; ++mf)
#pragma unroll
        for (int jf = 0; jf < 4; ++jf)
          s[mf][jf] = __builtin_amdgcn_mfma_f32_16x16x32_bf16(qf[mf][tt], kf[jf], s[mf][jf], 0, 0, 0);
    }

    const bool diag = (jt == ntiles - 1);
#pragma unroll
    for (int mf = 0; mf < 2; ++mf)
#pragma unroll
      for (int jf = 0; jf < 4; ++jf)
#pragma unroll
        for (int r = 0; r < 4; ++r) {
          float x = s[mf][jf][r] * frs[mf][r];
          if (diag && (j0 + jf * 16 + la) >= (i0 + mf * 16 + lb * 4 + r)) x = -1e30f;
          s[mf][jf][r] = x;
        }

#pragma unroll
    for (int mf = 0; mf < 2; ++mf)
#pragma unroll
      for (int r = 0; r < 4; ++r) {
        float pm = fmaxf(fmaxf(s[mf][0][r], s[mf][1][r]), fmaxf(s[mf][2][r], s[mf][3][r]));
        pm = fmaxf(pm, __shfl_xor(pm, 1));
        pm = fmaxf(pm, __shfl_xor(pm, 2));
        pm = fmaxf(pm, __shfl_xor(pm, 4));
        pm = fmaxf(pm, __shfl_xor(pm, 8));
        const float mo = mrun[mf][r];
        const float mn = fmaxf(mo, pm);
        const float sc = __expf(mo - mn);
        mrun[mf][r] = mn;
        float rs = 0.0f;
#pragma unroll
        for (int jf = 0; jf < 4; ++jf) {
          const float p = __expf(s[mf][jf][r] - mn);
          s[mf][jf][r] = p;
          rs += p;
        }
        rs += __shfl_xor(rs, 1);
        rs += __shfl_xor(rs, 2);
        rs += __shfl_xor(rs, 4);
        rs += __shfl_xor(rs, 8);
        lrun[mf][r] = lrun[mf][r] * sc + rs;
#pragma unroll
        for (int df = 0; df < 4; ++df) o[mf][df][r] *= sc;
      }

    // P tile is wave-private LDS; same-wave ds_write->ds_read, no barrier
#pragma unroll
    for (int mf = 0; mf < 2; ++mf)
#pragma unroll
      for (int jf = 0; jf < 4; ++jf)
#pragma unroll
        for (int r = 0; r < 4; ++r)
          P[(mf * 16 + lb * 4 + r) * 72 + jf * 16 + la] = f2bf(s[mf][jf][r]);

#pragma unroll
    for (int tt = 0; tt < 2; ++tt) {
      short8 pf[2], vf[4];
#pragma unroll
      for (int mf = 0; mf < 2; ++mf)
        pf[mf] = *(const short8*)&P[(mf * 16 + la) * 72 + tt * 32 + lb * 8];
#pragma unroll
      for (int df = 0; df < 4; ++df)
        vf[df] = *(const short8*)&vt[vbase + (long)(df * 16 + la) * Sq + j0 + tt * 32 + lb * 8];
#pragma unroll
      for (int mf = 0; mf < 2; ++mf)
#pragma unroll
        for (int df = 0; df < 4; ++df)
          o[mf][df] = __builtin_amdgcn_mfma_f32_16x16x32_bf16(pf[mf], vf[df], o[mf][df], 0, 0, 0);
    }
  }

#pragma unroll
  for (int mf = 0; mf < 2; ++mf)
#pragma unroll
    for (int df = 0; df < 4; ++df)
#pragma unroll
      for (int r = 0; r < 4; ++r) {
        const int ii = i0 + mf * 16 + lb * 4 + r;
        const float vv = (ii == 0) ? 0.0f : o[mf][df][r] / lrun[mf][r];
        ao[((long)b * Sq + ii) * Dq + h * 64 + df * 16 + la] = f2bf(vv);
      }
}

// ---------------------------------------------------------------------------
// Fused residual-add + LayerNorm, bf16 residual stream (r13):
// v = prev + add (+ add2); y = LN(v)*g + b -> out. final_: d_out per flags.
// ---------------------------------------------------------------------------
__global__ __launch_bounds__(256) void ln_kernel(
    const ushort_t* __restrict__ prev, const ushort_t* __restrict__ add,
    const ushort_t* __restrict__ add2,
    const ushort_t* __restrict__ g, const ushort_t* __restrict__ bb,
    ushort_t* __restrict__ outb, float* __restrict__ outf,
    const int* __restrict__ flags, int final_)
{
  __shared__ float red[2][4];
  const long row = blockIdx.x;
  const int t = threadIdx.x;
  const int c = t * 4;

  ushortx4 pv = *(const ushortx4*)&prev[row * Dq + c];
  ushortx4 av = *(const ushortx4*)&add[row * Dq + c];
  ushortx4 a2v;
  if (add2) a2v = *(const ushortx4*)&add2[row * Dq + c];
  float v[4];
  float s1 = 0.f, s2 = 0.f;
#pragma unroll
  for (int e = 0; e < 4; ++e) {
    float av_ = bf2f(av[e]);
    if (add2) av_ += bf2f(a2v[e]);
    v[e] = bf2f(pv[e]) + av_;
    s1 += v[e];
    s2 += v[e] * v[e];
  }
#pragma unroll
  for (int m = 1; m < 64; m <<= 1) {
    s1 += __shfl_xor(s1, m);
    s2 += __shfl_xor(s2, m);
  }
  const int lane = t & 63, w = t >> 6;
  if (lane == 0) { red[0][w] = s1; red[1][w] = s2; }
  __syncthreads();
  s1 = red[0][0] + red[0][1] + red[0][2] + red[0][3];
  s2 = red[1][0] + red[1][1] + red[1][2] + red[1][3];
  const float mean = s1 * (1.0f / Dq);
  const float var = fmaxf(s2 * (1.0f / Dq) - mean * mean, 0.0f);
  const float rstd = rsqrtf(var + 1e-5f);
  ushortx4 gv = *(const ushortx4*)&g[c];
  ushortx4 bv = *(const ushortx4*)&bb[c];
  ushortx4 ob;
  floatx4 xo;
#pragma unroll
  for (int e = 0; e < 4; ++e) {
    const float y = (v[e] - mean) * rstd * bf2f(gv[e]) + bf2f(bv[e]);
    xo[e] = y;
    ob[e] = f2bf(y);
  }
  if (final_ && !flags[0]) {
    *(floatx4*)&outf[row * Dq + c] = xo;
  } else {
    *(ushortx4*)&outb[row * Dq + c] = ob;
  }
}

// x = qe + pe (bf16), y = qa + pe (bf16); flag-aware source dtype
__global__ __launch_bounds__(256) void addpe_kernel(
    const void* __restrict__ qe, const void* __restrict__ qa,
    const void* __restrict__ pe,
    ushort_t* __restrict__ xb, ushort_t* __restrict__ yb,
    const int* __restrict__ flags)
{
  const long i = ((long)blockIdx.x * 256 + threadIdx.x) * 8;
  const long sd = i & ((long)Sq * Dq - 1);
  const bool isb = flags[0] != 0;
  float q[8], a[8], p[8];
  if (isb) {
    ushortx8 q8 = *(const ushortx8*)((const ushort_t*)qe + i);
    ushortx8 a8 = *(const ushortx8*)((const ushort_t*)qa + i);
    ushortx8 p8 = *(const ushortx8*)((const ushort_t*)pe + sd);
#pragma unroll
    for (int e = 0; e < 8; ++e) { q[e] = bf2f(q8[e]); a[e] = bf2f(a8[e]); p[e] = bf2f(p8[e]); }
  } else {
    const float* qp = (const float*)qe + i;
    const float* ap = (const float*)qa + i;
    const float* pp = (const float*)pe + sd;
    floatx4 q0 = *(const floatx4*)qp, q1 = *(const floatx4*)(qp + 4);
    floatx4 a0 = *(const floatx4*)ap, a1 = *(const floatx4*)(ap + 4);
    floatx4 p0 = *(const floatx4*)pp, p1 = *(const floatx4*)(pp + 4);
#pragma unroll
    for (int e = 0; e < 4; ++e) {
      q[e] = q0[e]; q[e + 4] = q1[e];
      a[e] = a0[e]; a[e + 4] = a1[e];
      p[e] = p0[e]; p[e + 4] = p1[e];
    }
  }
  ushortx8 xo, yo;
#pragma unroll
  for (int e = 0; e < 8; ++e) {
    const float xvv = (isb ? q[e] : bf2f(f2bf(q[e]))) + (isb ? p[e] : bf2f(f2bf(p[e])));
    const float yvv = (isb ? a[e] : bf2f(f2bf(a[e]))) + (isb ? p[e] : bf2f(f2bf(p[e])));
    xo[e] = f2bf(xvv);
    yo[e] = f2bf(yvv);
  }
  *(ushortx8*)&xb[i] = xo;
  *(ushortx8*)&yb[i] = yo;
}

// dst[z][n][k] = src[z][k][n]; flag-aware source dtype (weights: flags[1])
__global__ __launch_bounds__(256) void transpose_kernel(
    const void* __restrict__ src, ushort_t* __restrict__ dst, int K, int N,
    const int* __restrict__ flags)
{
  __shared__ __align__(16) ushort_t tile[64][72];
  const bool isb = flags[1] != 0;
  const long base = (long)blockIdx.z * K * N;
  const int k0 = blockIdx.y * 64, n0 = blockIdx.x * 64;
  const int t = threadIdx.x;
  const int r = t >> 3;
  const int cc = (t & 7) << 3;
#pragma unroll
  for (int it = 0; it < 2; ++it) {
    const int rr = r + it * 32;
    const long gi = base + (long)(k0 + rr) * N + n0 + cc;
    if (isb) {
      *(short8*)&tile[rr][cc] = *(const short8*)((const ushort_t*)src + gi);
    } else {
      const float* sf = (const float*)src + gi;
      floatx4 v0 = *(const floatx4*)sf;
      floatx4 v1 = *(const floatx4*)(sf + 4);
#pragma unroll
      for (int e = 0; e < 4; ++e) {
        tile[rr][cc + e] = f2bf(v0[e]);
        tile[rr][cc + 4 + e] = f2bf(v1[e]);
      }
    }
  }
  __syncthreads();
#pragma unroll
  for (int it = 0; it < 2; ++it) {
    const int rr = r + it * 32;
    short8 v;
#pragma unroll
    for (int e = 0; e < 8; ++e) v[e] = (short)tile[cc + e][rr];
    *(short8*)&dst[base + (long)(n0 + rr) * K + k0 + cc] = v;
  }
}

// vt[b][h][d][j] = vb[b][j][h*64+d]  (vb is bf16 workspace, no flag needed)
__global__ __launch_bounds__(256) void vtrans_kernel(
    const ushort_t* __restrict__ vb, ushort_t* __restrict__ vt)
{
  __shared__ __align__(16) ushort_t tile[64][72];
  const int b = blockIdx.y >> 4, h = blockIdx.y & 15;
  const int j0 = blockIdx.x * 64;
  const int t = threadIdx.x;
  const int r = t >> 3;
  const int cc = (t & 7) << 3;
#pragma unroll
  for (int it = 0; it < 2; ++it) {
    const int rr = r + it * 32;
    *(short8*)&tile[rr][cc] = *(const short8*)&vb[((long)b * Sq + j0 + rr) * Dq + h * 64 + cc];
  }
  __syncthreads();
#pragma unroll
  for (int it = 0; it < 2; ++it) {
    const int rr = r + it * 32;
    short8 v;
#pragma unroll
    for (int e = 0; e < 8; ++e) v[e] = (short)tile[cc + e][rr];
    *(short8*)&vt[((long)(b * Hq + h) * 64 + rr) * Sq + j0 + cc] = v;
  }
}

extern "C" void kernel_launch(void* const* d_in, const int* in_sizes, int n_in,
                              void* d_out, int out_size, void* d_ws, size_t ws_size,
                              hipStream_t stream)
{
  if (n_in < 18) return;
  const void* qe  = d_in[0];
  const void* qa  = d_in[1];
  const void* fr  = d_in[2];
  const void* pe  = d_in[3];
  const void* Wk  = d_in[4];
  const void* bk  = d_in[5];
  const void* Wv  = d_in[6];
  const void* bv  = d_in[7];
  const void* Wo  = d_in[8];
  const void* bo  = d_in[9];
  const void* W1  = d_in[10];
  const void* b1  = d_in[11];
  const void* W2  = d_in[12];
  const void* b2  = d_in[13];
  const void* g1  = d_in[14];
  const void* be1 = d_in[15];
  const void* g2  = d_in[16];
  const void* be2 = d_in[17];

  char* ws = (char*)d_ws;
  const size_t SM = 243269632L;
  const size_t NEED = SM + 114752L;
  if (ws_size < NEED) return;

  ushort_t* xb   = (ushort_t*)(ws + 33554432L);   // bf16 residual / GEMM input
  ushort_t* yb   = (ushort_t*)(ws + 50331648L);
  ushort_t* tmpD = (ushort_t*)(ws + 67108864L);
  ushort_t* WkT  = (ushort_t*)(ws + 83886080L);
  ushort_t* WvT  = (ushort_t*)(ws + 92274688L);
  ushort_t* WoT  = (ushort_t*)(ws + 100663296L);
  ushort_t* W1T  = (ushort_t*)(ws + 109051904L);
  ushort_t* W2T  = (ushort_t*)(ws + 142606336L);
  ushort_t* kb   = (ushort_t*)(ws + 176160768L);
  ushort_t* vbf  = (ushort_t*)(ws + 192937984L);
  ushort_t* vtb  = (ushort_t*)(ws + 209715200L);  // V^T; split-K partial slab after attn
  ushort_t* ff1  = kb;  // 64 MiB region, disjoint lifetime

  int*      flags = (int*)(ws + SM);
  ushort_t* frc  = (ushort_t*)(ws + SM + 64);
  ushort_t* bkc  = (ushort_t*)(ws + SM + 16448);
  ushort_t* bvc  = (ushort_t*)(ws + SM + 24640);
  ushort_t* boc  = (ushort_t*)(ws + SM + 32832);
  ushort_t* b1c  = (ushort_t*)(ws + SM + 41024);
  ushort_t* b2c  = (ushort_t*)(ws + SM + 73792);
  ushort_t* g1c  = (ushort_t*)(ws + SM + 81984);
  ushort_t* be1c = (ushort_t*)(ws + SM + 90176);
  ushort_t* g2c  = (ushort_t*)(ws + SM + 98368);
  ushort_t* be2c = (ushort_t*)(ws + SM + 106560);

  probe_kernel<<<1, 64, 0, stream>>>((const ushort_t*)pe, (const ushort_t*)g1, flags);

  {
    CvtArgs a;
    const void* srcs[10] = {fr, bk, bv, bo, b1, b2, g1, be1, g2, be2};
    ushort_t*   dsts[10] = {frc, bkc, bvc, boc, b1c, b2c, g1c, be1c, g2c, be2c};
    const int   ns[10]   = {8192, 4096, 4096, 4096, 16384, 4096, 4096, 4096, 4096, 4096};
    int cum = 0;
    for (int s = 0; s < 10; ++s) {
      a.src[s] = srcs[s]; a.dst[s] = dsts[s]; a.n[s] = ns[s];
      a.fi[s] = (s == 0) ? 0 : 1;
      a.cum[s] = cum;
      cum += (ns[s] + 255) / 256;
    }
    a.cum[10] = cum;
    convert_all_kernel<<<cum, 256, 0, stream>>>(a, flags);
  }

  transpose_kernel<<<dim3(16, 16, 4), 256, 0, stream>>>(Wk, WkT, 1024, 1024, flags);
  transpose_kernel<<<dim3(16, 16, 4), 256, 0, stream>>>(Wv, WvT, 1024, 1024, flags);
  transpose_kernel<<<dim3(16, 16, 4), 256, 0, stream>>>(Wo, WoT, 1024, 1024, flags);
  transpose_kernel<<<dim3(64, 16, 4), 256, 0, stream>>>(W1, W1T, 1024, 4096, flags);
  transpose_kernel<<<dim3(16, 64, 4), 256, 0, stream>>>(W2, W2T, 4096, 1024, flags);

  addpe_kernel<<<4096, 256, 0, stream>>>(qe, qa, pe, xb, yb, flags);

  for (int l = 0; l < 4; ++l) {
    // K-proj (z=0) + V-proj (z=1): 512 blocks
    gemm256_kernel<<<dim3(8, 32, 2), 256, 0, stream>>>(
        xb, WkT + (long)l * 1048576, bkc + l * 1024, kb, 0,
        yb, WvT + (long)l * 1048576, bvc + l * 1024, vbf, 0,
        1024, 1024, 1024, 0);
    vtrans_kernel<<<dim3(8, 256), 256, 0, stream>>>(vbf, vtb);
    attn_kernel<<<dim3(256, 16), 64, 0, stream>>>(kb, vtb, frc, vbf);  // ao aliases vbf
    // Wo: split-K=2, partial to vtb (dead after attn) -> 512 blocks
    gemm256_kernel<<<dim3(8, 32, 2), 256, 0, stream>>>(
        vbf, WoT + (long)l * 1048576, boc + l * 1024, tmpD, 0,
        vbf, WoT + (long)l * 1048576, nullptr,        vtb,  512,
        1024, 1024, 512, 0);
    ln_kernel<<<8192, 256, 0, stream>>>(xb, tmpD, vtb, g1c + l * 1024, be1c + l * 1024,
                                        xb, nullptr, flags, 0);
    // FF1: 1024 blocks
    gemm256_kernel<<<dim3(32, 32, 1), 256, 0, stream>>>(
        xb, W1T + (long)l * 4194304, b1c + l * 4096, ff1, 0,
        xb, W1T + (long)l * 4194304, b1c + l * 4096, ff1, 0,
        4096, 1024, 1024, 1);
    // FF2: split-K=2, partial to vtb -> 512 blocks
    gemm256_kernel<<<dim3(8, 32, 2), 256, 0, stream>>>(
        ff1, W2T + (long)l * 4194304, b2c + l * 1024, tmpD, 0,
        ff1, W2T + (long)l * 4194304, nullptr,        vtb,  2048,
        1024, 4096, 2048, 0);
    if (l == 3) {
      ln_kernel<<<8192, 256, 0, stream>>>(xb, tmpD, vtb, g2c + l * 1024, be2c + l * 1024,
                                          (ushort_t*)d_out, (float*)d_out, flags, 1);
    } else {
      ln_kernel<<<8192, 256, 0, stream>>>(xb, tmpD, vtb, g2c + l * 1024, be2c + l * 1024,
                                          xb, nullptr, flags, 0);
    }
  }
}